// Round 4
// baseline (14530.688 us; speedup 1.0000x reference)
//
#include <hip/hip_runtime.h>

// Problem constants (fixed by the reference)
#define NN 50000
#define TT 200
#define HH 128
#define EE 1600000

// Gate pre-scale constants: i,f,o scaled by -log2(e) so sigmoid = rcp(1+exp2(x));
// g scaled by +2*log2(e) so tanh = 1-2*rcp(exp2(x)+1). Cell state c stays true-scale.
#define NL2E  -1.4426950408889634f
#define TWOL2E 2.8853900817779268f

#define STR 136

typedef _Float16 f16x8 __attribute__((ext_vector_type(8)));
typedef float f32x4 __attribute__((ext_vector_type(4)));

__device__ __forceinline__ float sg2(float x) {          // sigmoid(z) for x = -log2e*z
    return __builtin_amdgcn_rcpf(1.f + exp2f(x));
}
__device__ __forceinline__ float th2(float x) {          // tanh(z) for x = 2*log2e*z
    return 1.f - 2.f * __builtin_amdgcn_rcpf(exp2f(x) + 1.f);
}
__device__ __forceinline__ f32x4 sg2_4(f32x4 x) {
    f32x4 r; r[0] = sg2(x[0]); r[1] = sg2(x[1]); r[2] = sg2(x[2]); r[3] = sg2(x[3]); return r;
}
__device__ __forceinline__ f32x4 th2_4(f32x4 x) {
    f32x4 r; r[0] = th2(x[0]); r[1] = th2(x[1]); r[2] = th2(x[2]); r[3] = th2(x[3]); return r;
}
__device__ __forceinline__ f32x4 splat4(float s) { f32x4 r = {s, s, s, s}; return r; }
__device__ __forceinline__ unsigned short f2h_bits(float x) {
    _Float16 h = (_Float16)x;
    union { _Float16 h; unsigned short u; } cv; cv.h = h; return cv.u;
}
__device__ __forceinline__ float h2f_bits(unsigned short u) {
    union { _Float16 h; unsigned short u; } cv; cv.u = u; return (float)cv.h;
}

// ---------------------------------------------------------------------------
// Weight packing: W is (512,128) row-major (PyTorch [4H, H]).
// MFMA-16x16x32 B-fragment order: tile jn (0..31 over gate-cols), chunk kk (0..3):
// out[(jn*4+kk)*512 + L*8 + i] = W[jn*16 + (L&15)][kk*32 + (L>>4)*8 + i]  (f16)
// Gate pre-scale folded in here (gate = jn>>3; order i,f,g,o).
// ---------------------------------------------------------------------------
__global__ void pack_w(const float* __restrict__ W, unsigned short* __restrict__ out) {
    int tile = blockIdx.x;          // jn*4 + kk
    int jn = tile >> 2, kk = tile & 3;
    int L = threadIdx.x;            // 0..63
    int n = jn * 16 + (L & 15);
    int k0 = kk * 32 + (L >> 4) * 8;
    float sc = ((jn >> 3) == 2) ? TWOL2E : NL2E;
    unsigned short* dst = out + (size_t)tile * 512 + L * 8;
#pragma unroll
    for (int i = 0; i < 8; ++i) dst[i] = f2h_bits(W[n * 128 + k0 + i] * sc);
}

__global__ void bias_prep(const float* __restrict__ bih0, const float* __restrict__ bhh0,
                          const float* __restrict__ bih1, const float* __restrict__ bhh1,
                          const float* __restrict__ wih0,
                          float* __restrict__ b0g, float* __restrict__ b1g, float* __restrict__ wxg) {
    int i = blockIdx.x * 256 + threadIdx.x;
    if (i < 512) {
        float sc = ((i >> 7) == 2) ? TWOL2E : NL2E;
        b0g[i] = (bih0[i] + bhh0[i]) * sc;
        b1g[i] = (bih1[i] + bhh1[i]) * sc;
        wxg[i] = wih0[i] * sc;
    }
}

// lightcurve [N][T] -> xT [T][N]
__global__ void transpose_lc(const float* __restrict__ lc, float* __restrict__ xT) {
    __shared__ float tile[32][33];
    int tx = threadIdx.x, ty = threadIdx.y;    // 32 x 8
    int n0 = blockIdx.y * 32, t0 = blockIdx.x * 32;
#pragma unroll
    for (int i = 0; i < 32; i += 8) {
        int n = n0 + ty + i, t = t0 + tx;
        if (n < NN && t < TT) tile[ty + i][tx] = lc[(size_t)n * TT + t];
    }
    __syncthreads();
#pragma unroll
    for (int i = 0; i < 32; i += 8) {
        int t = t0 + ty + i, n = n0 + tx;
        if (n < NN && t < TT) xT[(size_t)t * NN + n] = tile[tx][ty + i];
    }
}

// ---------------------------------------------------------------------------
// Fused 2-layer LSTM. Block = 512 threads (8 waves), TWO 32-node tiles (A,B),
// 200 steps. Round-0 two-barrier phase structure. The two tiles give each
// wave two independent instruction streams per phase (intra-wave ILP to hide
// ds_read/MFMA/trans latency at 1 block/CU), halve barriers per node, and
// share each weight B-fragment load across both tiles.
// ---------------------------------------------------------------------------

#define MFMA16(A, B, C) __builtin_amdgcn_mfma_f32_16x16x32_f16((A), (B), (C), 0, 0, 0)

#define DECLACC(S) f32x4 aI0##S = {}, aI1##S = {}, aF0##S = {}, aF1##S = {}, \
                         aG0##S = {}, aG1##S = {}, aO0##S = {}, aO1##S = {};

// One tile's MFMAs for one 32-wide K-chunk (B-frags passed in registers)
#define MMCT(S, HB, KK, BI, BF, BG, BO) {                                      \
    f16x8 a0_ = *reinterpret_cast<const f16x8*>(&(HB)[col][(KK) * 32 + quad * 8]);      \
    f16x8 a1_ = *reinterpret_cast<const f16x8*>(&(HB)[16 + col][(KK) * 32 + quad * 8]); \
    aI0##S = MFMA16(a0_, BI, aI0##S); aI1##S = MFMA16(a1_, BI, aI1##S);        \
    aF0##S = MFMA16(a0_, BF, aF0##S); aF1##S = MFMA16(a1_, BF, aF1##S);        \
    aG0##S = MFMA16(a0_, BG, aG0##S); aG1##S = MFMA16(a1_, BG, aG1##S);        \
    aO0##S = MFMA16(a0_, BO, aO0##S); aO1##S = MFMA16(a1_, BO, aO1##S);        \
}

// Load 4 gate B-frags once, apply to both tiles (16 MFMAs)
#define MMC2(HA, HBT, PI, PF, PG, PO, KK) {                                    \
    f16x8 bI_ = *reinterpret_cast<const f16x8*>((PI) + (KK) * 512);            \
    f16x8 bF_ = *reinterpret_cast<const f16x8*>((PF) + (KK) * 512);            \
    f16x8 bG_ = *reinterpret_cast<const f16x8*>((PG) + (KK) * 512);            \
    f16x8 bO_ = *reinterpret_cast<const f16x8*>((PO) + (KK) * 512);            \
    MMCT(A, HA, KK, bI_, bF_, bG_, bO_)                                        \
    MMCT(B, HBT, KK, bI_, bF_, bG_, bO_)                                       \
}

// Layer-0 activation, rowtile RT, x from xs[XO + ...]
#define ACT0N(RT, C, H, AI, AF, AG, AO, XO) {                                  \
    f32x4 xv_ = *reinterpret_cast<const f32x4*>(&xs[(XO) + (RT) * 16 + quad * 4]); \
    f32x4 gi_ = AI + splat4(B0I) + xv_ * splat4(WXI);                          \
    f32x4 gf_ = AF + splat4(B0F) + xv_ * splat4(WXF);                          \
    f32x4 gg_ = AG + splat4(B0G) + xv_ * splat4(WXG);                          \
    f32x4 go_ = AO + splat4(B0O) + xv_ * splat4(WXO);                          \
    C = sg2_4(gf_) * C + sg2_4(gi_) * th2_4(gg_);                              \
    H = sg2_4(go_) * th2_4(C * splat4(TWOL2E));                                \
}

// Layer-1 activation
#define ACT1N(C, H, AI, AF, AG, AO) {                                          \
    f32x4 gi_ = AI + splat4(B1I);                                              \
    f32x4 gf_ = AF + splat4(B1F);                                              \
    f32x4 gg_ = AG + splat4(B1G);                                              \
    f32x4 go_ = AO + splat4(B1O);                                              \
    C = sg2_4(gf_) * C + sg2_4(gi_) * th2_4(gg_);                              \
    H = sg2_4(go_) * th2_4(C * splat4(TWOL2E));                                \
}

// Write rowtile RT of this wave's h (f16) into LDS buffer
#define WRH(HB, RT, H)                                                         \
    (HB)[(RT) * 16 + quad * 4 + 0][j_] = f2h_bits((H)[0]);                     \
    (HB)[(RT) * 16 + quad * 4 + 1][j_] = f2h_bits((H)[1]);                     \
    (HB)[(RT) * 16 + quad * 4 + 2][j_] = f2h_bits((H)[2]);                     \
    (HB)[(RT) * 16 + quad * 4 + 3][j_] = f2h_bits((H)[3]);

// One timestep for both tiles: PB = write buffer (t&1), RB = read buffer
#define STEP(PB, RB, T)                                                        \
    {   /* layer 0: gates = h1_old @ Whh0^T + x*wih0 + b0 */                   \
        DECLACC(A) DECLACC(B)                                                  \
        MMC2(h1sA[RB], h1sB[RB], p0I, p0F, p0G, p0O, 0)                        \
        MMC2(h1sA[RB], h1sB[RB], p0I, p0F, p0G, p0O, 1)                        \
        MMC2(h1sA[RB], h1sB[RB], p0I, p0F, p0G, p0O, 2)                        \
        MMC2(h1sA[RB], h1sB[RB], p0I, p0F, p0G, p0O, 3)                        \
        f32x4 h1v0A, h1v1A, h1v0B, h1v1B;                                      \
        ACT0N(0, c1_0A, h1v0A, aI0A, aF0A, aG0A, aO0A, 0)                      \
        ACT0N(1, c1_1A, h1v1A, aI1A, aF1A, aG1A, aO1A, 0)                      \
        ACT0N(0, c1_0B, h1v0B, aI0B, aF0B, aG0B, aO0B, 32)                     \
        ACT0N(1, c1_1B, h1v1B, aI1B, aF1B, aG1B, aO1B, 32)                     \
        WRH(h1sA[PB], 0, h1v0A)                                                \
        WRH(h1sA[PB], 1, h1v1A)                                                \
        WRH(h1sB[PB], 0, h1v0B)                                                \
        WRH(h1sB[PB], 1, h1v1B)                                                \
    }                                                                          \
    __syncthreads();                                                           \
    {   /* layer 1: gates = h1_new @ Wih1^T + h2_old @ Whh1^T + b1 */          \
        DECLACC(A) DECLACC(B)                                                  \
        MMC2(h1sA[PB], h1sB[PB], u0I, u0F, u0G, u0O, 0)                        \
        MMC2(h1sA[PB], h1sB[PB], u0I, u0F, u0G, u0O, 1)                        \
        MMC2(h1sA[PB], h1sB[PB], u0I, u0F, u0G, u0O, 2)                        \
        MMC2(h1sA[PB], h1sB[PB], u0I, u0F, u0G, u0O, 3)                        \
        MMC2(h2sA[RB], h2sB[RB], v0I, v0F, v0G, v0O, 0)                        \
        MMC2(h2sA[RB], h2sB[RB], v0I, v0F, v0G, v0O, 1)                        \
        MMC2(h2sA[RB], h2sB[RB], v0I, v0F, v0G, v0O, 2)                        \
        MMC2(h2sA[RB], h2sB[RB], v0I, v0F, v0G, v0O, 3)                        \
        if (tid < 64) {   /* prefetch x[T+1] for both tiles while ACT runs */  \
            int n_ = n0 + tid;                                                 \
            xs[tid] = ((T) + 1 < TT && n_ < NN)                                \
                          ? xT[(size_t)((T) + 1) * NN + n_] : 0.f;             \
        }                                                                      \
        f32x4 h2v0A, h2v1A, h2v0B, h2v1B;                                      \
        ACT1N(c2_0A, h2v0A, aI0A, aF0A, aG0A, aO0A)                            \
        ACT1N(c2_1A, h2v1A, aI1A, aF1A, aG1A, aO1A)                            \
        ACT1N(c2_0B, h2v0B, aI0B, aF0B, aG0B, aO0B)                            \
        ACT1N(c2_1B, h2v1B, aI1B, aF1B, aG1B, aO1B)                            \
        WRH(h2sA[PB], 0, h2v0A)                                                \
        WRH(h2sA[PB], 1, h2v1A)                                                \
        WRH(h2sB[PB], 0, h2v0B)                                                \
        WRH(h2sB[PB], 1, h2v1B)                                                \
    }                                                                          \
    __syncthreads();

__global__ __launch_bounds__(512, 2) void lstm_kernel(
    const float* __restrict__ xT,
    const unsigned short* __restrict__ w0p,
    const unsigned short* __restrict__ w1ip,
    const unsigned short* __restrict__ w1hp,
    const float* __restrict__ b0g, const float* __restrict__ b1g,
    const float* __restrict__ wxg,
    float* __restrict__ h2out) {
    __shared__ unsigned short h1sA[2][32][STR];   // double-buffered, f16
    __shared__ unsigned short h2sA[2][32][STR];
    __shared__ unsigned short h1sB[2][32][STR];
    __shared__ unsigned short h2sB[2][32][STR];
    __shared__ __align__(16) float xs[64];        // x for both tiles

    const int tid = threadIdx.x;
    const int w = tid >> 6;          // wave id 0..7 == col-group jt
    const int lane = tid & 63;
    const int col = lane & 15;
    const int quad = lane >> 4;
    const int n0 = blockIdx.x * 64;
    const int j_ = w * 16 + col;     // this lane's hidden column

    for (int i = tid; i < 2 * 32 * STR; i += 512) {
        (&h1sA[0][0][0])[i] = 0; (&h2sA[0][0][0])[i] = 0;
        (&h1sB[0][0][0])[i] = 0; (&h2sB[0][0][0])[i] = 0;
    }
    if (tid < 64) { int n = n0 + tid; xs[tid] = (n < NN) ? xT[n] : 0.f; }

    // Per-lane bias/x-weight registers (loaded once; shared by both tiles)
    const float B0I = b0g[j_], B0F = b0g[128 + j_], B0G = b0g[256 + j_], B0O = b0g[384 + j_];
    const float B1I = b1g[j_], B1F = b1g[128 + j_], B1G = b1g[256 + j_], B1O = b1g[384 + j_];
    const float WXI = wxg[j_], WXF = wxg[128 + j_], WXG = wxg[256 + j_], WXO = wxg[384 + j_];

    // B-fragment base pointers (gate g tile = 8g + jt; tile stride 2048 ushorts)
    const unsigned short* p0I = w0p + (size_t)w * 2048 + lane * 8;
    const unsigned short* p0F = w0p + (size_t)(8 + w) * 2048 + lane * 8;
    const unsigned short* p0G = w0p + (size_t)(16 + w) * 2048 + lane * 8;
    const unsigned short* p0O = w0p + (size_t)(24 + w) * 2048 + lane * 8;
    const unsigned short* u0I = w1ip + (size_t)w * 2048 + lane * 8;
    const unsigned short* u0F = w1ip + (size_t)(8 + w) * 2048 + lane * 8;
    const unsigned short* u0G = w1ip + (size_t)(16 + w) * 2048 + lane * 8;
    const unsigned short* u0O = w1ip + (size_t)(24 + w) * 2048 + lane * 8;
    const unsigned short* v0I = w1hp + (size_t)w * 2048 + lane * 8;
    const unsigned short* v0F = w1hp + (size_t)(8 + w) * 2048 + lane * 8;
    const unsigned short* v0G = w1hp + (size_t)(16 + w) * 2048 + lane * 8;
    const unsigned short* v0O = w1hp + (size_t)(24 + w) * 2048 + lane * 8;

    // persistent cell state: 8 f32x4 = 32 regs (two tiles)
    f32x4 c1_0A = {}, c1_1A = {}, c2_0A = {}, c2_1A = {};
    f32x4 c1_0B = {}, c1_1B = {}, c2_0B = {}, c2_1B = {};

    __syncthreads();

#pragma unroll 1
    for (int tt = 0; tt < TT; tt += 2) {
        STEP(0, 1, tt)
        STEP(1, 0, tt + 1)
    }

    // final h2 lives in buffer 1 (last step wrote PB=1); cooperative write-out
    for (int i = tid; i < 64 * 128; i += 512) {
        int m = i >> 7, j = i & 127;
        int n = n0 + m;
        if (n < NN) {
            unsigned short v = (m < 32) ? h2sA[1][m][j] : h2sB[1][m - 32][j];
            h2out[(size_t)n * HH + j] = h2f_bits(v);
        }
    }
}

// ---------------------------------------------------------------------------
// GCN pieces (fp32)
// ---------------------------------------------------------------------------
__global__ void deg_init(float* __restrict__ deg) {
    int i = blockIdx.x * 256 + threadIdx.x;
    if (i < NN) deg[i] = 1.f;   // self loop
}
__global__ void deg_edges(const int* __restrict__ ei, float* __restrict__ deg) {
    int e = blockIdx.x * 256 + threadIdx.x;
    if (e < EE) unsafeAtomicAdd(&deg[ei[EE + e]], 1.f);   // col = target
}
__global__ void dinv_k(const float* __restrict__ deg, float* __restrict__ dinv) {
    int i = blockIdx.x * 256 + threadIdx.x;
    if (i < NN) dinv[i] = rsqrtf(fmaxf(deg[i], 1.f));
}

// exclusive scan of per-node in-edge counts (deg-1) -> off[0..NN]
__global__ void scan_off(const float* __restrict__ deg, int* __restrict__ off) {
    __shared__ int sp[256];
    const int tid = threadIdx.x;
    const int chunk = (NN + 255) / 256;
    const int i0 = tid * chunk;
    int s = 0;
    for (int i = 0; i < chunk; ++i) {
        int idx = i0 + i;
        if (idx < NN) s += (int)deg[idx] - 1;
    }
    sp[tid] = s;
    __syncthreads();
    for (int o = 1; o < 256; o <<= 1) {
        int v = (tid >= o) ? sp[tid - o] : 0;
        __syncthreads();
        sp[tid] += v;
        __syncthreads();
    }
    int run = sp[tid] - s;
    for (int i = 0; i < chunk; ++i) {
        int idx = i0 + i;
        if (idx < NN) { off[idx] = run; run += (int)deg[idx] - 1; }
    }
    if (tid == 255) off[NN] = sp[255];
}

__global__ void csr_fill(const int* __restrict__ ei, const float* __restrict__ dinv,
                         const int* __restrict__ off, int* __restrict__ cur,
                         int* __restrict__ crow, float* __restrict__ cw) {
    int e = blockIdx.x * 256 + threadIdx.x;
    if (e >= EE) return;
    int r = ei[e], c = ei[EE + e];
    int p = atomicAdd(&cur[c], 1);
    int idx = off[c] + p;
    crow[idx] = r;
    cw[idx] = dinv[r] * dinv[c];
}

// hw = h @ Wg   ([N,128] x [128,128]); 32 nodes per block
__global__ void gcn_gemm(const float* __restrict__ h, const float* __restrict__ Wg,
                         float* __restrict__ hw) {
    __shared__ float hsT[128][36];
    int tid = threadIdx.x;
    int n0 = blockIdx.x * 32;
#pragma unroll
    for (int c = 0; c < 16; ++c) {
        int lin = c * 256 + tid;
        int m = lin >> 7, k = lin & 127;
        int n = n0 + m;
        hsT[k][m] = (n < NN) ? h[(size_t)n * HH + k] : 0.f;
    }
    __syncthreads();
    int j = tid & 127, p = tid >> 7;
    float acc[16];
#pragma unroll
    for (int m = 0; m < 16; ++m) acc[m] = 0.f;
    for (int k = 0; k < 128; ++k) {
        float wg = Wg[k * 128 + j];
        const float4* hp = reinterpret_cast<const float4*>(&hsT[k][p * 16]);
        float4 a = hp[0], b = hp[1], c = hp[2], d = hp[3];
        acc[0]  += a.x * wg; acc[1]  += a.y * wg; acc[2]  += a.z * wg; acc[3]  += a.w * wg;
        acc[4]  += b.x * wg; acc[5]  += b.y * wg; acc[6]  += b.z * wg; acc[7]  += b.w * wg;
        acc[8]  += c.x * wg; acc[9]  += c.y * wg; acc[10] += c.z * wg; acc[11] += c.w * wg;
        acc[12] += d.x * wg; acc[13] += d.y * wg; acc[14] += d.z * wg; acc[15] += d.w * wg;
    }
#pragma unroll
    for (int m = 0; m < 16; ++m) {
        int n = n0 + p * 16 + m;
        if (n < NN) hw[(size_t)n * HH + j] = acc[m];
    }
}

// Fused: self-loop + CSR gather + bias + LayerNorm + ReLU + residual
__global__ __launch_bounds__(256) void gcn_agg(
    const float* __restrict__ hw, const int* __restrict__ off,
    const int* __restrict__ crow, const float* __restrict__ cw,
    const float* __restrict__ dinv, const float* __restrict__ bg,
    const float* __restrict__ gamma, const float* __restrict__ beta,
    float* __restrict__ h) {
    __shared__ float xch[4][2];
    const int tid = threadIdx.x;
    const int half = tid >> 7;
    const int f = tid & 127;
    const int v = blockIdx.x * 2 + half;
    const float d = dinv[v];
    float acc = bg[f] + d * d * hw[v * HH + f];
    const int s1 = off[v + 1];
    for (int s = off[v]; s < s1; ++s) {
        int r = crow[s];
        float wv = cw[s];
        acc = fmaf(wv, hw[r * HH + f], acc);
    }
    float sum = acc, sq = acc * acc;
#pragma unroll
    for (int o = 32; o; o >>= 1) { sum += __shfl_xor(sum, o); sq += __shfl_xor(sq, o); }
    int wid = tid >> 6;
    if ((tid & 63) == 0) { xch[wid][0] = sum; xch[wid][1] = sq; }
    __syncthreads();
    sum += xch[wid ^ 1][0]; sq += xch[wid ^ 1][1];
    float mu = sum * (1.f / 128.f);
    float var = sq * (1.f / 128.f) - mu * mu;
    float rn = rsqrtf(var + 1e-5f);
    float o = (acc - mu) * rn * gamma[f] + beta[f];
    h[v * HH + f] = fmaxf(o, 0.f) + h[v * HH + f];
}

__global__ void pool_k(const float* __restrict__ h, float* __restrict__ pooled) {
    int j = threadIdx.x & 127, p = threadIdx.x >> 7;
    float s = 0.f;
    for (int n = blockIdx.x * 2 + p; n < NN; n += 512) s += h[(size_t)n * HH + j];
    unsafeAtomicAdd(&pooled[j], s);
}

__global__ void final_k(const float* __restrict__ pooled, const float* __restrict__ Wout,
                        const float* __restrict__ bout, float* __restrict__ out) {
    int lane = threadIdx.x;
    float s = pooled[lane] * Wout[lane] + pooled[lane + 64] * Wout[lane + 64];
#pragma unroll
    for (int o = 32; o; o >>= 1) s += __shfl_xor(s, o);
    if (lane == 0) out[0] = s * (1.f / (float)NN) + bout[0];
}

// ---------------------------------------------------------------------------
extern "C" void kernel_launch(void* const* d_in, const int* in_sizes, int n_in,
                              void* d_out, int out_size, void* d_ws, size_t ws_size,
                              hipStream_t stream) {
    const float* lc   = (const float*)d_in[0];
    const int*   ei   = (const int*)d_in[1];
    const float* Wih0 = (const float*)d_in[2];
    const float* Whh0 = (const float*)d_in[3];
    const float* bih0 = (const float*)d_in[4];
    const float* bhh0 = (const float*)d_in[5];
    const float* Wih1 = (const float*)d_in[6];
    const float* Whh1 = (const float*)d_in[7];
    const float* bih1 = (const float*)d_in[8];
    const float* bhh1 = (const float*)d_in[9];
    const float* Wout = (const float*)d_in[22];
    const float* bout = (const float*)d_in[23];
    float* out = (float*)d_out;

    float* ws   = (float*)d_ws;
    float* h    = ws;
    float* hw   = ws + 6400000;
    float* xT   = ws + 6400000;                    // aliases hw+CSR region pre-LSTM
    int*   off  = (int*)(ws + 12800000);
    int*   cur  = off + 50048;
    int*   crow = cur + 50048;
    float* cw   = (float*)(crow + EE);
    float* P      = ws + 16400064;
    float* deg    = P;
    float* dinv   = deg + 50000;
    float* b0g    = dinv + 50000;
    float* b1g    = b0g + 512;
    float* wxg    = b1g + 512;
    float* pooled = wxg + 512;
    unsigned short* w0p  = (unsigned short*)(pooled + 128);
    unsigned short* w1ip = w0p + 65536;
    unsigned short* w1hp = w1ip + 65536;

    pack_w<<<128, 64, 0, stream>>>(Whh0, w0p);
    pack_w<<<128, 64, 0, stream>>>(Wih1, w1ip);
    pack_w<<<128, 64, 0, stream>>>(Whh1, w1hp);
    bias_prep<<<2, 256, 0, stream>>>(bih0, bhh0, bih1, bhh1, Wih0, b0g, b1g, wxg);
    {
        dim3 g((TT + 31) / 32, (NN + 31) / 32), b(32, 8);
        transpose_lc<<<g, b, 0, stream>>>(lc, xT);
    }
    deg_init<<<(NN + 255) / 256, 256, 0, stream>>>(deg);
    deg_edges<<<(EE + 255) / 256, 256, 0, stream>>>(ei, deg);
    dinv_k<<<(NN + 255) / 256, 256, 0, stream>>>(deg, dinv);

    lstm_kernel<<<(NN + 63) / 64, 512, 0, stream>>>(xT, w0p, w1ip, w1hp, b0g, b1g, wxg, h);

    hipMemsetAsync(cur, 0, 50000 * sizeof(int), stream);
    scan_off<<<1, 256, 0, stream>>>(deg, off);
    csr_fill<<<(EE + 255) / 256, 256, 0, stream>>>(ei, dinv, off, cur, crow, cw);

    for (int l = 0; l < 3; ++l) {
        const float* Wg = (const float*)d_in[10 + 4 * l];
        const float* bg = (const float*)d_in[11 + 4 * l];
        const float* gm = (const float*)d_in[12 + 4 * l];
        const float* bt = (const float*)d_in[13 + 4 * l];
        gcn_gemm<<<(NN + 31) / 32, 256, 0, stream>>>(h, Wg, hw);
        gcn_agg<<<NN / 2, 256, 0, stream>>>(hw, off, crow, cw, dinv, bg, gm, bt, h);
    }

    hipMemsetAsync(pooled, 0, HH * sizeof(float), stream);
    pool_k<<<256, 256, 0, stream>>>(h, pooled);
    final_k<<<1, 64, 0, stream>>>(pooled, Wout, bout, out);
}

// Round 5
// 14289.351 us; speedup vs baseline: 1.0169x; 1.0169x over previous
//
#include <hip/hip_runtime.h>

// Problem constants (fixed by the reference)
#define NN 50000
#define TT 200
#define HH 128
#define EE 1600000

// Gate pre-scale constants: i,f,o scaled by -log2(e) so sigmoid = rcp(1+exp2(x));
// g scaled by +2*log2(e) so tanh = 1-2*rcp(exp2(x)+1). Cell state c stays true-scale.
// Verified absmax=0.0 in rounds 1-4.
#define NL2E  -1.4426950408889634f
#define TWOL2E 2.8853900817779268f

#define STR 136

typedef _Float16 f16x8 __attribute__((ext_vector_type(8)));
typedef float f32x4 __attribute__((ext_vector_type(4)));

__device__ __forceinline__ float sg2(float x) {          // sigmoid(z) for x = -log2e*z
    return __builtin_amdgcn_rcpf(1.f + exp2f(x));
}
__device__ __forceinline__ float th2(float x) {          // tanh(z) for x = 2*log2e*z
    return 1.f - 2.f * __builtin_amdgcn_rcpf(exp2f(x) + 1.f);
}
__device__ __forceinline__ f32x4 sg2_4(f32x4 x) {
    f32x4 r; r[0] = sg2(x[0]); r[1] = sg2(x[1]); r[2] = sg2(x[2]); r[3] = sg2(x[3]); return r;
}
__device__ __forceinline__ f32x4 th2_4(f32x4 x) {
    f32x4 r; r[0] = th2(x[0]); r[1] = th2(x[1]); r[2] = th2(x[2]); r[3] = th2(x[3]); return r;
}
__device__ __forceinline__ f32x4 splat4(float s) { f32x4 r = {s, s, s, s}; return r; }
__device__ __forceinline__ unsigned short f2h_bits(float x) {
    _Float16 h = (_Float16)x;
    union { _Float16 h; unsigned short u; } cv; cv.h = h; return cv.u;
}
__device__ __forceinline__ float h2f_bits(unsigned short u) {
    union { _Float16 h; unsigned short u; } cv; cv.u = u; return (float)cv.h;
}

// ---------------------------------------------------------------------------
// Weight packing: W is (512,128) row-major (PyTorch [4H, H]).
// MFMA-16x16x32 B-fragment order: tile jn (0..31 over gate-cols), chunk kk (0..3):
// out[(jn*4+kk)*512 + L*8 + i] = W[jn*16 + (L&15)][kk*32 + (L>>4)*8 + i]  (f16)
// Gate pre-scale folded in here (gate = jn>>3; order i,f,g,o).
// ---------------------------------------------------------------------------
__global__ void pack_w(const float* __restrict__ W, unsigned short* __restrict__ out) {
    int tile = blockIdx.x;          // jn*4 + kk
    int jn = tile >> 2, kk = tile & 3;
    int L = threadIdx.x;            // 0..63
    int n = jn * 16 + (L & 15);
    int k0 = kk * 32 + (L >> 4) * 8;
    float sc = ((jn >> 3) == 2) ? TWOL2E : NL2E;
    unsigned short* dst = out + (size_t)tile * 512 + L * 8;
#pragma unroll
    for (int i = 0; i < 8; ++i) dst[i] = f2h_bits(W[n * 128 + k0 + i] * sc);
}

__global__ void bias_prep(const float* __restrict__ bih0, const float* __restrict__ bhh0,
                          const float* __restrict__ bih1, const float* __restrict__ bhh1,
                          const float* __restrict__ wih0,
                          float* __restrict__ b0g, float* __restrict__ b1g, float* __restrict__ wxg) {
    int i = blockIdx.x * 256 + threadIdx.x;
    if (i < 512) {
        float sc = ((i >> 7) == 2) ? TWOL2E : NL2E;
        b0g[i] = (bih0[i] + bhh0[i]) * sc;
        b1g[i] = (bih1[i] + bhh1[i]) * sc;
        wxg[i] = wih0[i] * sc;
    }
}

// lightcurve [N][T] -> xT [T][N]
__global__ void transpose_lc(const float* __restrict__ lc, float* __restrict__ xT) {
    __shared__ float tile[32][33];
    int tx = threadIdx.x, ty = threadIdx.y;    // 32 x 8
    int n0 = blockIdx.y * 32, t0 = blockIdx.x * 32;
#pragma unroll
    for (int i = 0; i < 32; i += 8) {
        int n = n0 + ty + i, t = t0 + tx;
        if (n < NN && t < TT) tile[ty + i][tx] = lc[(size_t)n * TT + t];
    }
    __syncthreads();
#pragma unroll
    for (int i = 0; i < 32; i += 8) {
        int t = t0 + ty + i, n = n0 + tx;
        if (n < NN && t < TT) xT[(size_t)t * NN + n] = tile[tx][ty + i];
    }
}

// ---------------------------------------------------------------------------
// Fused 2-layer LSTM. Round-0 structure: block = 512 threads (8 waves),
// 32 nodes, 200 steps, two barriers per step. Changes vs round 0 (both
// register-neutral, numerics verified): exp2-prescaled gates; biases/wih0
// in per-lane registers instead of LDS staging.
// ---------------------------------------------------------------------------

#define MFMA16(A, B, C) __builtin_amdgcn_mfma_f32_16x16x32_f16((A), (B), (C), 0, 0, 0)

// One 32-wide K-chunk: 4 B-frags (gates), 2 A-frags (row tiles), 8 MFMAs
#define MMC(HB, PI, PF, PG, PO, KK) {                                          \
    f16x8 bI_ = *reinterpret_cast<const f16x8*>((PI) + (KK) * 512);            \
    f16x8 bF_ = *reinterpret_cast<const f16x8*>((PF) + (KK) * 512);            \
    f16x8 bG_ = *reinterpret_cast<const f16x8*>((PG) + (KK) * 512);            \
    f16x8 bO_ = *reinterpret_cast<const f16x8*>((PO) + (KK) * 512);            \
    f16x8 a0_ = *reinterpret_cast<const f16x8*>(&(HB)[col][(KK) * 32 + quad * 8]);      \
    f16x8 a1_ = *reinterpret_cast<const f16x8*>(&(HB)[16 + col][(KK) * 32 + quad * 8]); \
    aI0 = MFMA16(a0_, bI_, aI0); aI1 = MFMA16(a1_, bI_, aI1);                  \
    aF0 = MFMA16(a0_, bF_, aF0); aF1 = MFMA16(a1_, bF_, aF1);                  \
    aG0 = MFMA16(a0_, bG_, aG0); aG1 = MFMA16(a1_, bG_, aG1);                  \
    aO0 = MFMA16(a0_, bO_, aO0); aO1 = MFMA16(a1_, bO_, aO1);                  \
}

// Activation with x*w_ih terms (layer 0), rowtile RT (rows RT*16+quad*4 ..+3)
#define ACT0N(RT, C, H, AI, AF, AG, AO) {                                      \
    f32x4 xv_ = *reinterpret_cast<const f32x4*>(&xs[(RT) * 16 + quad * 4]);    \
    f32x4 gi_ = AI + splat4(B0I) + xv_ * splat4(WXI);                          \
    f32x4 gf_ = AF + splat4(B0F) + xv_ * splat4(WXF);                          \
    f32x4 gg_ = AG + splat4(B0G) + xv_ * splat4(WXG);                          \
    f32x4 go_ = AO + splat4(B0O) + xv_ * splat4(WXO);                          \
    C = sg2_4(gf_) * C + sg2_4(gi_) * th2_4(gg_);                              \
    H = sg2_4(go_) * th2_4(C * splat4(TWOL2E));                                \
}

// Activation, no x terms (layer 1)
#define ACT1N(C, H, AI, AF, AG, AO) {                                          \
    f32x4 gi_ = AI + splat4(B1I);                                              \
    f32x4 gf_ = AF + splat4(B1F);                                              \
    f32x4 gg_ = AG + splat4(B1G);                                              \
    f32x4 go_ = AO + splat4(B1O);                                              \
    C = sg2_4(gf_) * C + sg2_4(gi_) * th2_4(gg_);                              \
    H = sg2_4(go_) * th2_4(C * splat4(TWOL2E));                                \
}

// Write rowtile RT of this wave's h (f16) into LDS buffer
#define WRH(HB, RT, H)                                                         \
    (HB)[(RT) * 16 + quad * 4 + 0][j_] = f2h_bits((H)[0]);                     \
    (HB)[(RT) * 16 + quad * 4 + 1][j_] = f2h_bits((H)[1]);                     \
    (HB)[(RT) * 16 + quad * 4 + 2][j_] = f2h_bits((H)[2]);                     \
    (HB)[(RT) * 16 + quad * 4 + 3][j_] = f2h_bits((H)[3]);

// One timestep: PB = write buffer (t&1), RB = read buffer (PB^1)
#define STEP(PB, RB, T)                                                        \
    {   /* layer 0: gates = h1_old @ Whh0^T + x*wih0 + b0 */                   \
        f32x4 aI0 = {}, aI1 = {}, aF0 = {}, aF1 = {};                          \
        f32x4 aG0 = {}, aG1 = {}, aO0 = {}, aO1 = {};                          \
        MMC(h1s[RB], p0I, p0F, p0G, p0O, 0)                                    \
        MMC(h1s[RB], p0I, p0F, p0G, p0O, 1)                                    \
        MMC(h1s[RB], p0I, p0F, p0G, p0O, 2)                                    \
        MMC(h1s[RB], p0I, p0F, p0G, p0O, 3)                                    \
        f32x4 h1v0, h1v1;                                                      \
        ACT0N(0, c1_0, h1v0, aI0, aF0, aG0, aO0)                               \
        ACT0N(1, c1_1, h1v1, aI1, aF1, aG1, aO1)                               \
        WRH(h1s[PB], 0, h1v0)                                                  \
        WRH(h1s[PB], 1, h1v1)                                                  \
    }                                                                          \
    __syncthreads();                                                           \
    {   /* layer 1: gates = h1_new @ Wih1^T + h2_old @ Whh1^T + b1 */          \
        f32x4 aI0 = {}, aI1 = {}, aF0 = {}, aF1 = {};                          \
        f32x4 aG0 = {}, aG1 = {}, aO0 = {}, aO1 = {};                          \
        MMC(h1s[PB], u0I, u0F, u0G, u0O, 0)                                    \
        MMC(h1s[PB], u0I, u0F, u0G, u0O, 1)                                    \
        MMC(h1s[PB], u0I, u0F, u0G, u0O, 2)                                    \
        MMC(h1s[PB], u0I, u0F, u0G, u0O, 3)                                    \
        MMC(h2s[RB], v0I, v0F, v0G, v0O, 0)                                    \
        MMC(h2s[RB], v0I, v0F, v0G, v0O, 1)                                    \
        MMC(h2s[RB], v0I, v0F, v0G, v0O, 2)                                    \
        MMC(h2s[RB], v0I, v0F, v0G, v0O, 3)                                    \
        if (tid < 32) {   /* prefetch x[T+1] while ACT runs */                 \
            int n_ = n0 + tid;                                                 \
            xs[tid] = ((T) + 1 < TT && n_ < NN)                                \
                          ? xT[(size_t)((T) + 1) * NN + n_] : 0.f;             \
        }                                                                      \
        f32x4 h2v0, h2v1;                                                      \
        ACT1N(c2_0, h2v0, aI0, aF0, aG0, aO0)                                  \
        ACT1N(c2_1, h2v1, aI1, aF1, aG1, aO1)                                  \
        WRH(h2s[PB], 0, h2v0)                                                  \
        WRH(h2s[PB], 1, h2v1)                                                  \
    }                                                                          \
    __syncthreads();

__global__ __launch_bounds__(512, 2) void lstm_kernel(
    const float* __restrict__ xT,
    const unsigned short* __restrict__ w0p,
    const unsigned short* __restrict__ w1ip,
    const unsigned short* __restrict__ w1hp,
    const float* __restrict__ b0g, const float* __restrict__ b1g,
    const float* __restrict__ wxg,
    float* __restrict__ h2out) {
    __shared__ unsigned short h1s[2][32][STR];   // double-buffered, f16
    __shared__ unsigned short h2s[2][32][STR];
    __shared__ __align__(16) float xs[32];

    const int tid = threadIdx.x;
    const int w = tid >> 6;          // wave id 0..7 == col-group jt
    const int lane = tid & 63;
    const int col = lane & 15;
    const int quad = lane >> 4;
    const int n0 = blockIdx.x * 32;
    const int j_ = w * 16 + col;     // this lane's hidden column

    for (int i = tid; i < 2 * 32 * STR; i += 512) {
        (&h1s[0][0][0])[i] = 0; (&h2s[0][0][0])[i] = 0;
    }
    if (tid < 32) { int n = n0 + tid; xs[tid] = (n < NN) ? xT[n] : 0.f; }

    // Per-lane bias / x-weight registers (loaded once, loop-invariant)
    const float B0I = b0g[j_], B0F = b0g[128 + j_], B0G = b0g[256 + j_], B0O = b0g[384 + j_];
    const float B1I = b1g[j_], B1F = b1g[128 + j_], B1G = b1g[256 + j_], B1O = b1g[384 + j_];
    const float WXI = wxg[j_], WXF = wxg[128 + j_], WXG = wxg[256 + j_], WXO = wxg[384 + j_];

    // B-fragment base pointers (gate g tile = 8g + jt; tile stride 2048 ushorts)
    const unsigned short* p0I = w0p + (size_t)w * 2048 + lane * 8;
    const unsigned short* p0F = w0p + (size_t)(8 + w) * 2048 + lane * 8;
    const unsigned short* p0G = w0p + (size_t)(16 + w) * 2048 + lane * 8;
    const unsigned short* p0O = w0p + (size_t)(24 + w) * 2048 + lane * 8;
    const unsigned short* u0I = w1ip + (size_t)w * 2048 + lane * 8;
    const unsigned short* u0F = w1ip + (size_t)(8 + w) * 2048 + lane * 8;
    const unsigned short* u0G = w1ip + (size_t)(16 + w) * 2048 + lane * 8;
    const unsigned short* u0O = w1ip + (size_t)(24 + w) * 2048 + lane * 8;
    const unsigned short* v0I = w1hp + (size_t)w * 2048 + lane * 8;
    const unsigned short* v0F = w1hp + (size_t)(8 + w) * 2048 + lane * 8;
    const unsigned short* v0G = w1hp + (size_t)(16 + w) * 2048 + lane * 8;
    const unsigned short* v0O = w1hp + (size_t)(24 + w) * 2048 + lane * 8;

    // persistent cell state: 4 f32x4 = 16 regs
    f32x4 c1_0 = {}, c1_1 = {}, c2_0 = {}, c2_1 = {};

    __syncthreads();

#pragma unroll 1
    for (int tt = 0; tt < TT; tt += 2) {
        STEP(0, 1, tt)
        STEP(1, 0, tt + 1)
    }

    // final h2 lives in buffer 1 (last step wrote PB=1); cooperative write-out
    for (int i = tid; i < 32 * 128; i += 512) {
        int m = i >> 7, j = i & 127;
        int n = n0 + m;
        if (n < NN) h2out[(size_t)n * HH + j] = h2f_bits(h2s[1][m][j]);
    }
}

// ---------------------------------------------------------------------------
// GCN pieces (fp32)
// ---------------------------------------------------------------------------
__global__ void deg_init(float* __restrict__ deg) {
    int i = blockIdx.x * 256 + threadIdx.x;
    if (i < NN) deg[i] = 1.f;   // self loop
}
__global__ void deg_edges(const int* __restrict__ ei, float* __restrict__ deg) {
    int e = blockIdx.x * 256 + threadIdx.x;
    if (e < EE) unsafeAtomicAdd(&deg[ei[EE + e]], 1.f);   // col = target
}
__global__ void dinv_k(const float* __restrict__ deg, float* __restrict__ dinv) {
    int i = blockIdx.x * 256 + threadIdx.x;
    if (i < NN) dinv[i] = rsqrtf(fmaxf(deg[i], 1.f));
}

// exclusive scan of per-node in-edge counts (deg-1) -> off[0..NN]
__global__ void scan_off(const float* __restrict__ deg, int* __restrict__ off) {
    __shared__ int sp[256];
    const int tid = threadIdx.x;
    const int chunk = (NN + 255) / 256;
    const int i0 = tid * chunk;
    int s = 0;
    for (int i = 0; i < chunk; ++i) {
        int idx = i0 + i;
        if (idx < NN) s += (int)deg[idx] - 1;
    }
    sp[tid] = s;
    __syncthreads();
    for (int o = 1; o < 256; o <<= 1) {
        int v = (tid >= o) ? sp[tid - o] : 0;
        __syncthreads();
        sp[tid] += v;
        __syncthreads();
    }
    int run = sp[tid] - s;
    for (int i = 0; i < chunk; ++i) {
        int idx = i0 + i;
        if (idx < NN) { off[idx] = run; run += (int)deg[idx] - 1; }
    }
    if (tid == 255) off[NN] = sp[255];
}

__global__ void csr_fill(const int* __restrict__ ei, const float* __restrict__ dinv,
                         const int* __restrict__ off, int* __restrict__ cur,
                         int* __restrict__ crow, float* __restrict__ cw) {
    int e = blockIdx.x * 256 + threadIdx.x;
    if (e >= EE) return;
    int r = ei[e], c = ei[EE + e];
    int p = atomicAdd(&cur[c], 1);
    int idx = off[c] + p;
    crow[idx] = r;
    cw[idx] = dinv[r] * dinv[c];
}

// hw = h @ Wg   ([N,128] x [128,128]); 32 nodes per block
__global__ void gcn_gemm(const float* __restrict__ h, const float* __restrict__ Wg,
                         float* __restrict__ hw) {
    __shared__ float hsT[128][36];
    int tid = threadIdx.x;
    int n0 = blockIdx.x * 32;
#pragma unroll
    for (int c = 0; c < 16; ++c) {
        int lin = c * 256 + tid;
        int m = lin >> 7, k = lin & 127;
        int n = n0 + m;
        hsT[k][m] = (n < NN) ? h[(size_t)n * HH + k] : 0.f;
    }
    __syncthreads();
    int j = tid & 127, p = tid >> 7;
    float acc[16];
#pragma unroll
    for (int m = 0; m < 16; ++m) acc[m] = 0.f;
    for (int k = 0; k < 128; ++k) {
        float wg = Wg[k * 128 + j];
        const float4* hp = reinterpret_cast<const float4*>(&hsT[k][p * 16]);
        float4 a = hp[0], b = hp[1], c = hp[2], d = hp[3];
        acc[0]  += a.x * wg; acc[1]  += a.y * wg; acc[2]  += a.z * wg; acc[3]  += a.w * wg;
        acc[4]  += b.x * wg; acc[5]  += b.y * wg; acc[6]  += b.z * wg; acc[7]  += b.w * wg;
        acc[8]  += c.x * wg; acc[9]  += c.y * wg; acc[10] += c.z * wg; acc[11] += c.w * wg;
        acc[12] += d.x * wg; acc[13] += d.y * wg; acc[14] += d.z * wg; acc[15] += d.w * wg;
    }
#pragma unroll
    for (int m = 0; m < 16; ++m) {
        int n = n0 + p * 16 + m;
        if (n < NN) hw[(size_t)n * HH + j] = acc[m];
    }
}

// Fused: self-loop + CSR gather + bias + LayerNorm + ReLU + residual
__global__ __launch_bounds__(256) void gcn_agg(
    const float* __restrict__ hw, const int* __restrict__ off,
    const int* __restrict__ crow, const float* __restrict__ cw,
    const float* __restrict__ dinv, const float* __restrict__ bg,
    const float* __restrict__ gamma, const float* __restrict__ beta,
    float* __restrict__ h) {
    __shared__ float xch[4][2];
    const int tid = threadIdx.x;
    const int half = tid >> 7;
    const int f = tid & 127;
    const int v = blockIdx.x * 2 + half;
    const float d = dinv[v];
    float acc = bg[f] + d * d * hw[v * HH + f];
    const int s1 = off[v + 1];
    for (int s = off[v]; s < s1; ++s) {
        int r = crow[s];
        float wv = cw[s];
        acc = fmaf(wv, hw[r * HH + f], acc);
    }
    float sum = acc, sq = acc * acc;
#pragma unroll
    for (int o = 32; o; o >>= 1) { sum += __shfl_xor(sum, o); sq += __shfl_xor(sq, o); }
    int wid = tid >> 6;
    if ((tid & 63) == 0) { xch[wid][0] = sum; xch[wid][1] = sq; }
    __syncthreads();
    sum += xch[wid ^ 1][0]; sq += xch[wid ^ 1][1];
    float mu = sum * (1.f / 128.f);
    float var = sq * (1.f / 128.f) - mu * mu;
    float rn = rsqrtf(var + 1e-5f);
    float o = (acc - mu) * rn * gamma[f] + beta[f];
    h[v * HH + f] = fmaxf(o, 0.f) + h[v * HH + f];
}

__global__ void pool_k(const float* __restrict__ h, float* __restrict__ pooled) {
    int j = threadIdx.x & 127, p = threadIdx.x >> 7;
    float s = 0.f;
    for (int n = blockIdx.x * 2 + p; n < NN; n += 512) s += h[(size_t)n * HH + j];
    unsafeAtomicAdd(&pooled[j], s);
}

__global__ void final_k(const float* __restrict__ pooled, const float* __restrict__ Wout,
                        const float* __restrict__ bout, float* __restrict__ out) {
    int lane = threadIdx.x;
    float s = pooled[lane] * Wout[lane] + pooled[lane + 64] * Wout[lane + 64];
#pragma unroll
    for (int o = 32; o; o >>= 1) s += __shfl_xor(s, o);
    if (lane == 0) out[0] = s * (1.f / (float)NN) + bout[0];
}

// ---------------------------------------------------------------------------
extern "C" void kernel_launch(void* const* d_in, const int* in_sizes, int n_in,
                              void* d_out, int out_size, void* d_ws, size_t ws_size,
                              hipStream_t stream) {
    const float* lc   = (const float*)d_in[0];
    const int*   ei   = (const int*)d_in[1];
    const float* Wih0 = (const float*)d_in[2];
    const float* Whh0 = (const float*)d_in[3];
    const float* bih0 = (const float*)d_in[4];
    const float* bhh0 = (const float*)d_in[5];
    const float* Wih1 = (const float*)d_in[6];
    const float* Whh1 = (const float*)d_in[7];
    const float* bih1 = (const float*)d_in[8];
    const float* bhh1 = (const float*)d_in[9];
    const float* Wout = (const float*)d_in[22];
    const float* bout = (const float*)d_in[23];
    float* out = (float*)d_out;

    float* ws   = (float*)d_ws;
    float* h    = ws;
    float* hw   = ws + 6400000;
    float* xT   = ws + 6400000;                    // aliases hw+CSR region pre-LSTM
    int*   off  = (int*)(ws + 12800000);
    int*   cur  = off + 50048;
    int*   crow = cur + 50048;
    float* cw   = (float*)(crow + EE);
    float* P      = ws + 16400064;
    float* deg    = P;
    float* dinv   = deg + 50000;
    float* b0g    = dinv + 50000;
    float* b1g    = b0g + 512;
    float* wxg    = b1g + 512;
    float* pooled = wxg + 512;
    unsigned short* w0p  = (unsigned short*)(pooled + 128);
    unsigned short* w1ip = w0p + 65536;
    unsigned short* w1hp = w1ip + 65536;

    pack_w<<<128, 64, 0, stream>>>(Whh0, w0p);
    pack_w<<<128, 64, 0, stream>>>(Wih1, w1ip);
    pack_w<<<128, 64, 0, stream>>>(Whh1, w1hp);
    bias_prep<<<2, 256, 0, stream>>>(bih0, bhh0, bih1, bhh1, Wih0, b0g, b1g, wxg);
    {
        dim3 g((TT + 31) / 32, (NN + 31) / 32), b(32, 8);
        transpose_lc<<<g, b, 0, stream>>>(lc, xT);
    }
    deg_init<<<(NN + 255) / 256, 256, 0, stream>>>(deg);
    deg_edges<<<(EE + 255) / 256, 256, 0, stream>>>(ei, deg);
    dinv_k<<<(NN + 255) / 256, 256, 0, stream>>>(deg, dinv);

    lstm_kernel<<<(NN + 31) / 32, 512, 0, stream>>>(xT, w0p, w1ip, w1hp, b0g, b1g, wxg, h);

    hipMemsetAsync(cur, 0, 50000 * sizeof(int), stream);
    scan_off<<<1, 256, 0, stream>>>(deg, off);
    csr_fill<<<(EE + 255) / 256, 256, 0, stream>>>(ei, dinv, off, cur, crow, cw);

    for (int l = 0; l < 3; ++l) {
        const float* Wg = (const float*)d_in[10 + 4 * l];
        const float* bg = (const float*)d_in[11 + 4 * l];
        const float* gm = (const float*)d_in[12 + 4 * l];
        const float* bt = (const float*)d_in[13 + 4 * l];
        gcn_gemm<<<(NN + 31) / 32, 256, 0, stream>>>(h, Wg, hw);
        gcn_agg<<<NN / 2, 256, 0, stream>>>(hw, off, crow, cw, dinv, bg, gm, bt, h);
    }

    hipMemsetAsync(pooled, 0, HH * sizeof(float), stream);
    pool_k<<<256, 256, 0, stream>>>(h, pooled);
    final_k<<<1, 64, 0, stream>>>(pooled, Wout, bout, out);
}

// Round 6
// 9242.867 us; speedup vs baseline: 1.5721x; 1.5460x over previous
//
#include <hip/hip_runtime.h>

// Problem constants (fixed by the reference)
#define NN 50000
#define TT 200
#define HH 128
#define EE 1600000

// Gate pre-scale constants: i,f,o scaled by -log2(e) so sigmoid = rcp(1+exp2(x));
// g scaled by +2*log2(e) so tanh = 1-2*rcp(exp2(x)+1). Cell state c stays true-scale.
// Numerics verified absmax=0.0 in rounds 1,2,5.
#define NL2E  -1.4426950408889634f
#define TWOL2E 2.8853900817779268f

typedef _Float16 f16x8 __attribute__((ext_vector_type(8)));
typedef float f32x4 __attribute__((ext_vector_type(4)));

__device__ __forceinline__ float sg2(float x) {          // sigmoid(z) for x = -log2e*z
    return __builtin_amdgcn_rcpf(1.f + exp2f(x));
}
__device__ __forceinline__ float th2(float x) {          // tanh(z) for x = 2*log2e*z
    return 1.f - 2.f * __builtin_amdgcn_rcpf(exp2f(x) + 1.f);
}
__device__ __forceinline__ f32x4 sg2_4(f32x4 x) {
    f32x4 r; r[0] = sg2(x[0]); r[1] = sg2(x[1]); r[2] = sg2(x[2]); r[3] = sg2(x[3]); return r;
}
__device__ __forceinline__ f32x4 th2_4(f32x4 x) {
    f32x4 r; r[0] = th2(x[0]); r[1] = th2(x[1]); r[2] = th2(x[2]); r[3] = th2(x[3]); return r;
}
__device__ __forceinline__ f32x4 splat4(float s) { f32x4 r = {s, s, s, s}; return r; }
__device__ __forceinline__ unsigned short f2h_bits(float x) {
    _Float16 h = (_Float16)x;
    union { _Float16 h; unsigned short u; } cv; cv.h = h; return cv.u;
}
__device__ __forceinline__ float h2f_bits(unsigned short u) {
    union { _Float16 h; unsigned short u; } cv; cv.u = u; return (float)cv.h;
}

// ---------------------------------------------------------------------------
// Weight packing: W is (512,128) row-major (PyTorch [4H, H]).
// MFMA-16x16x32 B-fragment order: tile jn (0..31 over gate-cols), chunk kk (0..3):
// out[(jn*4+kk)*512 + L*8 + i] = W[jn*16 + (L&15)][kk*32 + (L>>4)*8 + i]  (f16)
// Gate pre-scale folded in here (gate = jn>>3; order i,f,g,o).
// ---------------------------------------------------------------------------
__global__ void pack_w(const float* __restrict__ W, unsigned short* __restrict__ out) {
    int tile = blockIdx.x;          // jn*4 + kk
    int jn = tile >> 2, kk = tile & 3;
    int L = threadIdx.x;            // 0..63
    int n = jn * 16 + (L & 15);
    int k0 = kk * 32 + (L >> 4) * 8;
    float sc = ((jn >> 3) == 2) ? TWOL2E : NL2E;
    unsigned short* dst = out + (size_t)tile * 512 + L * 8;
#pragma unroll
    for (int i = 0; i < 8; ++i) dst[i] = f2h_bits(W[n * 128 + k0 + i] * sc);
}

__global__ void bias_prep(const float* __restrict__ bih0, const float* __restrict__ bhh0,
                          const float* __restrict__ bih1, const float* __restrict__ bhh1,
                          const float* __restrict__ wih0,
                          float* __restrict__ b0g, float* __restrict__ b1g, float* __restrict__ wxg) {
    int i = blockIdx.x * 256 + threadIdx.x;
    if (i < 512) {
        float sc = ((i >> 7) == 2) ? TWOL2E : NL2E;
        b0g[i] = (bih0[i] + bhh0[i]) * sc;
        b1g[i] = (bih1[i] + bhh1[i]) * sc;
        wxg[i] = wih0[i] * sc;
    }
}

// lightcurve [N][T] -> xT [T][N]
__global__ void transpose_lc(const float* __restrict__ lc, float* __restrict__ xT) {
    __shared__ float tile[32][33];
    int tx = threadIdx.x, ty = threadIdx.y;    // 32 x 8
    int n0 = blockIdx.y * 32, t0 = blockIdx.x * 32;
#pragma unroll
    for (int i = 0; i < 32; i += 8) {
        int n = n0 + ty + i, t = t0 + tx;
        if (n < NN && t < TT) tile[ty + i][tx] = lc[(size_t)n * TT + t];
    }
    __syncthreads();
#pragma unroll
    for (int i = 0; i < 32; i += 8) {
        int t = t0 + ty + i, n = n0 + tx;
        if (n < NN && t < TT) xT[(size_t)t * NN + n] = tile[tx][ty + i];
    }
}

// ---------------------------------------------------------------------------
// Fused 2-layer LSTM. Block = 512 threads (8 waves), 32 nodes, 200 steps.
// Round-0 structure EXACTLY (two barriers/step, biases staged in LDS — this
// staging is load-bearing for the register allocation; do NOT move biases to
// registers, it spills: r5). Only change vs round 0: exp2-prescaled gates
// (fewer VALU ops in ACT, zero register-pressure change).
// ---------------------------------------------------------------------------

#define MFMA16(A, B, C) __builtin_amdgcn_mfma_f32_16x16x32_f16((A), (B), (C), 0, 0, 0)

// One 32-wide K-chunk: 4 B-frags (gates), 2 A-frags (row tiles), 8 MFMAs
#define MMC(HB, PI, PF, PG, PO, KK) {                                          \
    f16x8 bI_ = *reinterpret_cast<const f16x8*>((PI) + (KK) * 512);            \
    f16x8 bF_ = *reinterpret_cast<const f16x8*>((PF) + (KK) * 512);            \
    f16x8 bG_ = *reinterpret_cast<const f16x8*>((PG) + (KK) * 512);            \
    f16x8 bO_ = *reinterpret_cast<const f16x8*>((PO) + (KK) * 512);            \
    f16x8 a0_ = *reinterpret_cast<const f16x8*>(&(HB)[col][(KK) * 32 + quad * 8]);      \
    f16x8 a1_ = *reinterpret_cast<const f16x8*>(&(HB)[16 + col][(KK) * 32 + quad * 8]); \
    aI0 = MFMA16(a0_, bI_, aI0); aI1 = MFMA16(a1_, bI_, aI1);                  \
    aF0 = MFMA16(a0_, bF_, aF0); aF1 = MFMA16(a1_, bF_, aF1);                  \
    aG0 = MFMA16(a0_, bG_, aG0); aG1 = MFMA16(a1_, bG_, aG1);                  \
    aO0 = MFMA16(a0_, bO_, aO0); aO1 = MFMA16(a1_, bO_, aO1);                  \
}

// Activation with x*w_ih terms (layer 0), rowtile RT (rows RT*16+quad*4 ..+3)
#define ACT0N(RT, C, H, AI, AF, AG, AO) {                                      \
    f32x4 xv_ = *reinterpret_cast<const f32x4*>(&xs[(RT) * 16 + quad * 4]);    \
    f32x4 gi_ = AI + splat4(bI) + xv_ * splat4(wI);                            \
    f32x4 gf_ = AF + splat4(bF) + xv_ * splat4(wF);                            \
    f32x4 gg_ = AG + splat4(bG) + xv_ * splat4(wG);                            \
    f32x4 go_ = AO + splat4(bO) + xv_ * splat4(wO);                            \
    C = sg2_4(gf_) * C + sg2_4(gi_) * th2_4(gg_);                              \
    H = sg2_4(go_) * th2_4(C * splat4(TWOL2E));                                \
}

// Activation, no x terms (layer 1)
#define ACT1N(C, H, AI, AF, AG, AO) {                                          \
    f32x4 gi_ = AI + splat4(bI);                                               \
    f32x4 gf_ = AF + splat4(bF);                                               \
    f32x4 gg_ = AG + splat4(bG);                                               \
    f32x4 go_ = AO + splat4(bO);                                               \
    C = sg2_4(gf_) * C + sg2_4(gi_) * th2_4(gg_);                              \
    H = sg2_4(go_) * th2_4(C * splat4(TWOL2E));                                \
}

// Write rowtile RT of this wave's h (f16) into LDS buffer
#define WRH(HB, RT, H)                                                         \
    (HB)[(RT) * 16 + quad * 4 + 0][j_] = f2h_bits((H)[0]);                     \
    (HB)[(RT) * 16 + quad * 4 + 1][j_] = f2h_bits((H)[1]);                     \
    (HB)[(RT) * 16 + quad * 4 + 2][j_] = f2h_bits((H)[2]);                     \
    (HB)[(RT) * 16 + quad * 4 + 3][j_] = f2h_bits((H)[3]);

// One timestep: PB = write buffer (t&1), RB = read buffer (PB^1)
#define STEP(PB, RB, T)                                                        \
    {   /* layer 0: gates = h1_old @ Whh0^T + x*wih0 + b0 */                   \
        f32x4 aI0 = {}, aI1 = {}, aF0 = {}, aF1 = {};                          \
        f32x4 aG0 = {}, aG1 = {}, aO0 = {}, aO1 = {};                          \
        MMC(h1s[RB], p0I, p0F, p0G, p0O, 0)                                    \
        MMC(h1s[RB], p0I, p0F, p0G, p0O, 1)                                    \
        MMC(h1s[RB], p0I, p0F, p0G, p0O, 2)                                    \
        MMC(h1s[RB], p0I, p0F, p0G, p0O, 3)                                    \
        const float bI = b0s[j_], bF = b0s[128 + j_];                          \
        const float bG = b0s[256 + j_], bO = b0s[384 + j_];                    \
        const float wI = wxs[j_], wF = wxs[128 + j_];                          \
        const float wG = wxs[256 + j_], wO = wxs[384 + j_];                    \
        f32x4 h1v0, h1v1;                                                      \
        ACT0N(0, c1_0, h1v0, aI0, aF0, aG0, aO0)                               \
        ACT0N(1, c1_1, h1v1, aI1, aF1, aG1, aO1)                               \
        WRH(h1s[PB], 0, h1v0)                                                  \
        WRH(h1s[PB], 1, h1v1)                                                  \
    }                                                                          \
    __syncthreads();                                                           \
    {   /* layer 1: gates = h1_new @ Wih1^T + h2_old @ Whh1^T + b1 */          \
        f32x4 aI0 = {}, aI1 = {}, aF0 = {}, aF1 = {};                          \
        f32x4 aG0 = {}, aG1 = {}, aO0 = {}, aO1 = {};                          \
        MMC(h1s[PB], u0I, u0F, u0G, u0O, 0)                                    \
        MMC(h1s[PB], u0I, u0F, u0G, u0O, 1)                                    \
        MMC(h1s[PB], u0I, u0F, u0G, u0O, 2)                                    \
        MMC(h1s[PB], u0I, u0F, u0G, u0O, 3)                                    \
        MMC(h2s[RB], v0I, v0F, v0G, v0O, 0)                                    \
        MMC(h2s[RB], v0I, v0F, v0G, v0O, 1)                                    \
        MMC(h2s[RB], v0I, v0F, v0G, v0O, 2)                                    \
        MMC(h2s[RB], v0I, v0F, v0G, v0O, 3)                                    \
        const float bI = b1s[j_], bF = b1s[128 + j_];                          \
        const float bG = b1s[256 + j_], bO = b1s[384 + j_];                    \
        f32x4 h2v0, h2v1;                                                      \
        ACT1N(c2_0, h2v0, aI0, aF0, aG0, aO0)                                  \
        ACT1N(c2_1, h2v1, aI1, aF1, aG1, aO1)                                  \
        WRH(h2s[PB], 0, h2v0)                                                  \
        WRH(h2s[PB], 1, h2v1)                                                  \
        if (tid < 32) {                                                        \
            int n_ = n0 + tid;                                                 \
            xs[tid] = ((T) + 1 < TT && n_ < NN)                                \
                          ? xT[(size_t)((T) + 1) * NN + n_] : 0.f;             \
        }                                                                      \
    }                                                                          \
    __syncthreads();

__global__ __launch_bounds__(512, 2) void lstm_kernel(
    const float* __restrict__ xT,
    const unsigned short* __restrict__ w0p,
    const unsigned short* __restrict__ w1ip,
    const unsigned short* __restrict__ w1hp,
    const float* __restrict__ b0g, const float* __restrict__ b1g,
    const float* __restrict__ wxg,
    float* __restrict__ h2out) {
    __shared__ unsigned short h1s[2][32][136];   // double-buffered, f16
    __shared__ unsigned short h2s[2][32][136];
    __shared__ __align__(16) float xs[32];
    __shared__ float b0s[512], b1s[512], wxs[512];

    const int tid = threadIdx.x;
    const int w = tid >> 6;          // wave id 0..7 == col-group jt
    const int lane = tid & 63;
    const int col = lane & 15;
    const int quad = lane >> 4;
    const int n0 = blockIdx.x * 32;
    const int j_ = w * 16 + col;     // this lane's hidden column

    for (int i = tid; i < 2 * 32 * 136; i += 512) {
        (&h1s[0][0][0])[i] = 0; (&h2s[0][0][0])[i] = 0;
    }
    if (tid < 512) { b0s[tid] = b0g[tid]; b1s[tid] = b1g[tid]; wxs[tid] = wxg[tid]; }
    if (tid < 32) { int n = n0 + tid; xs[tid] = (n < NN) ? xT[n] : 0.f; }

    // B-fragment base pointers (gate g tile = 8g + jt; tile stride 2048 ushorts)
    const unsigned short* p0I = w0p + (size_t)w * 2048 + lane * 8;
    const unsigned short* p0F = w0p + (size_t)(8 + w) * 2048 + lane * 8;
    const unsigned short* p0G = w0p + (size_t)(16 + w) * 2048 + lane * 8;
    const unsigned short* p0O = w0p + (size_t)(24 + w) * 2048 + lane * 8;
    const unsigned short* u0I = w1ip + (size_t)w * 2048 + lane * 8;
    const unsigned short* u0F = w1ip + (size_t)(8 + w) * 2048 + lane * 8;
    const unsigned short* u0G = w1ip + (size_t)(16 + w) * 2048 + lane * 8;
    const unsigned short* u0O = w1ip + (size_t)(24 + w) * 2048 + lane * 8;
    const unsigned short* v0I = w1hp + (size_t)w * 2048 + lane * 8;
    const unsigned short* v0F = w1hp + (size_t)(8 + w) * 2048 + lane * 8;
    const unsigned short* v0G = w1hp + (size_t)(16 + w) * 2048 + lane * 8;
    const unsigned short* v0O = w1hp + (size_t)(24 + w) * 2048 + lane * 8;

    // persistent cell state: 4 f32x4 = 16 regs
    f32x4 c1_0 = {}, c1_1 = {}, c2_0 = {}, c2_1 = {};

    __syncthreads();

#pragma unroll 1
    for (int tt = 0; tt < TT; tt += 2) {
        STEP(0, 1, tt)
        STEP(1, 0, tt + 1)
    }

    // final h2 lives in buffer 1 (last step wrote PB=1); cooperative write-out
    for (int i = tid; i < 32 * 128; i += 512) {
        int m = i >> 7, j = i & 127;
        int n = n0 + m;
        if (n < NN) h2out[(size_t)n * HH + j] = h2f_bits(h2s[1][m][j]);
    }
}

// ---------------------------------------------------------------------------
// GCN pieces (fp32)
// ---------------------------------------------------------------------------
__global__ void deg_init(float* __restrict__ deg) {
    int i = blockIdx.x * 256 + threadIdx.x;
    if (i < NN) deg[i] = 1.f;   // self loop
}
__global__ void deg_edges(const int* __restrict__ ei, float* __restrict__ deg) {
    int e = blockIdx.x * 256 + threadIdx.x;
    if (e < EE) unsafeAtomicAdd(&deg[ei[EE + e]], 1.f);   // col = target
}
__global__ void dinv_k(const float* __restrict__ deg, float* __restrict__ dinv) {
    int i = blockIdx.x * 256 + threadIdx.x;
    if (i < NN) dinv[i] = rsqrtf(fmaxf(deg[i], 1.f));
}

// exclusive scan of per-node in-edge counts (deg-1) -> off[0..NN]
__global__ void scan_off(const float* __restrict__ deg, int* __restrict__ off) {
    __shared__ int sp[256];
    const int tid = threadIdx.x;
    const int chunk = (NN + 255) / 256;
    const int i0 = tid * chunk;
    int s = 0;
    for (int i = 0; i < chunk; ++i) {
        int idx = i0 + i;
        if (idx < NN) s += (int)deg[idx] - 1;
    }
    sp[tid] = s;
    __syncthreads();
    for (int o = 1; o < 256; o <<= 1) {
        int v = (tid >= o) ? sp[tid - o] : 0;
        __syncthreads();
        sp[tid] += v;
        __syncthreads();
    }
    int run = sp[tid] - s;
    for (int i = 0; i < chunk; ++i) {
        int idx = i0 + i;
        if (idx < NN) { off[idx] = run; run += (int)deg[idx] - 1; }
    }
    if (tid == 255) off[NN] = sp[255];
}

__global__ void csr_fill(const int* __restrict__ ei, const float* __restrict__ dinv,
                         const int* __restrict__ off, int* __restrict__ cur,
                         int* __restrict__ crow, float* __restrict__ cw) {
    int e = blockIdx.x * 256 + threadIdx.x;
    if (e >= EE) return;
    int r = ei[e], c = ei[EE + e];
    int p = atomicAdd(&cur[c], 1);
    int idx = off[c] + p;
    crow[idx] = r;
    cw[idx] = dinv[r] * dinv[c];
}

// hw = h @ Wg   ([N,128] x [128,128]); 32 nodes per block
__global__ void gcn_gemm(const float* __restrict__ h, const float* __restrict__ Wg,
                         float* __restrict__ hw) {
    __shared__ float hsT[128][36];
    int tid = threadIdx.x;
    int n0 = blockIdx.x * 32;
#pragma unroll
    for (int c = 0; c < 16; ++c) {
        int lin = c * 256 + tid;
        int m = lin >> 7, k = lin & 127;
        int n = n0 + m;
        hsT[k][m] = (n < NN) ? h[(size_t)n * HH + k] : 0.f;
    }
    __syncthreads();
    int j = tid & 127, p = tid >> 7;
    float acc[16];
#pragma unroll
    for (int m = 0; m < 16; ++m) acc[m] = 0.f;
    for (int k = 0; k < 128; ++k) {
        float wg = Wg[k * 128 + j];
        const float4* hp = reinterpret_cast<const float4*>(&hsT[k][p * 16]);
        float4 a = hp[0], b = hp[1], c = hp[2], d = hp[3];
        acc[0]  += a.x * wg; acc[1]  += a.y * wg; acc[2]  += a.z * wg; acc[3]  += a.w * wg;
        acc[4]  += b.x * wg; acc[5]  += b.y * wg; acc[6]  += b.z * wg; acc[7]  += b.w * wg;
        acc[8]  += c.x * wg; acc[9]  += c.y * wg; acc[10] += c.z * wg; acc[11] += c.w * wg;
        acc[12] += d.x * wg; acc[13] += d.y * wg; acc[14] += d.z * wg; acc[15] += d.w * wg;
    }
#pragma unroll
    for (int m = 0; m < 16; ++m) {
        int n = n0 + p * 16 + m;
        if (n < NN) hw[(size_t)n * HH + j] = acc[m];
    }
}

// Fused: self-loop + CSR gather + bias + LayerNorm + ReLU + residual
__global__ __launch_bounds__(256) void gcn_agg(
    const float* __restrict__ hw, const int* __restrict__ off,
    const int* __restrict__ crow, const float* __restrict__ cw,
    const float* __restrict__ dinv, const float* __restrict__ bg,
    const float* __restrict__ gamma, const float* __restrict__ beta,
    float* __restrict__ h) {
    __shared__ float xch[4][2];
    const int tid = threadIdx.x;
    const int half = tid >> 7;
    const int f = tid & 127;
    const int v = blockIdx.x * 2 + half;
    const float d = dinv[v];
    float acc = bg[f] + d * d * hw[v * HH + f];
    const int s1 = off[v + 1];
    for (int s = off[v]; s < s1; ++s) {
        int r = crow[s];
        float wv = cw[s];
        acc = fmaf(wv, hw[r * HH + f], acc);
    }
    float sum = acc, sq = acc * acc;
#pragma unroll
    for (int o = 32; o; o >>= 1) { sum += __shfl_xor(sum, o); sq += __shfl_xor(sq, o); }
    int wid = tid >> 6;
    if ((tid & 63) == 0) { xch[wid][0] = sum; xch[wid][1] = sq; }
    __syncthreads();
    sum += xch[wid ^ 1][0]; sq += xch[wid ^ 1][1];
    float mu = sum * (1.f / 128.f);
    float var = sq * (1.f / 128.f) - mu * mu;
    float rn = rsqrtf(var + 1e-5f);
    float o = (acc - mu) * rn * gamma[f] + beta[f];
    h[v * HH + f] = fmaxf(o, 0.f) + h[v * HH + f];
}

__global__ void pool_k(const float* __restrict__ h, float* __restrict__ pooled) {
    int j = threadIdx.x & 127, p = threadIdx.x >> 7;
    float s = 0.f;
    for (int n = blockIdx.x * 2 + p; n < NN; n += 512) s += h[(size_t)n * HH + j];
    unsafeAtomicAdd(&pooled[j], s);
}

__global__ void final_k(const float* __restrict__ pooled, const float* __restrict__ Wout,
                        const float* __restrict__ bout, float* __restrict__ out) {
    int lane = threadIdx.x;
    float s = pooled[lane] * Wout[lane] + pooled[lane + 64] * Wout[lane + 64];
#pragma unroll
    for (int o = 32; o; o >>= 1) s += __shfl_xor(s, o);
    if (lane == 0) out[0] = s * (1.f / (float)NN) + bout[0];
}

// ---------------------------------------------------------------------------
extern "C" void kernel_launch(void* const* d_in, const int* in_sizes, int n_in,
                              void* d_out, int out_size, void* d_ws, size_t ws_size,
                              hipStream_t stream) {
    const float* lc   = (const float*)d_in[0];
    const int*   ei   = (const int*)d_in[1];
    const float* Wih0 = (const float*)d_in[2];
    const float* Whh0 = (const float*)d_in[3];
    const float* bih0 = (const float*)d_in[4];
    const float* bhh0 = (const float*)d_in[5];
    const float* Wih1 = (const float*)d_in[6];
    const float* Whh1 = (const float*)d_in[7];
    const float* bih1 = (const float*)d_in[8];
    const float* bhh1 = (const float*)d_in[9];
    const float* Wout = (const float*)d_in[22];
    const float* bout = (const float*)d_in[23];
    float* out = (float*)d_out;

    float* ws   = (float*)d_ws;
    float* h    = ws;
    float* hw   = ws + 6400000;
    float* xT   = ws + 6400000;                    // aliases hw+CSR region pre-LSTM
    int*   off  = (int*)(ws + 12800000);
    int*   cur  = off + 50048;
    int*   crow = cur + 50048;
    float* cw   = (float*)(crow + EE);
    float* P      = ws + 16400064;
    float* deg    = P;
    float* dinv   = deg + 50000;
    float* b0g    = dinv + 50000;
    float* b1g    = b0g + 512;
    float* wxg    = b1g + 512;
    float* pooled = wxg + 512;
    unsigned short* w0p  = (unsigned short*)(pooled + 128);
    unsigned short* w1ip = w0p + 65536;
    unsigned short* w1hp = w1ip + 65536;

    pack_w<<<128, 64, 0, stream>>>(Whh0, w0p);
    pack_w<<<128, 64, 0, stream>>>(Wih1, w1ip);
    pack_w<<<128, 64, 0, stream>>>(Whh1, w1hp);
    bias_prep<<<2, 256, 0, stream>>>(bih0, bhh0, bih1, bhh1, Wih0, b0g, b1g, wxg);
    {
        dim3 g((TT + 31) / 32, (NN + 31) / 32), b(32, 8);
        transpose_lc<<<g, b, 0, stream>>>(lc, xT);
    }
    deg_init<<<(NN + 255) / 256, 256, 0, stream>>>(deg);
    deg_edges<<<(EE + 255) / 256, 256, 0, stream>>>(ei, deg);
    dinv_k<<<(NN + 255) / 256, 256, 0, stream>>>(deg, dinv);

    lstm_kernel<<<(NN + 31) / 32, 512, 0, stream>>>(xT, w0p, w1ip, w1hp, b0g, b1g, wxg, h);

    hipMemsetAsync(cur, 0, 50000 * sizeof(int), stream);
    scan_off<<<1, 256, 0, stream>>>(deg, off);
    csr_fill<<<(EE + 255) / 256, 256, 0, stream>>>(ei, dinv, off, cur, crow, cw);

    for (int l = 0; l < 3; ++l) {
        const float* Wg = (const float*)d_in[10 + 4 * l];
        const float* bg = (const float*)d_in[11 + 4 * l];
        const float* gm = (const float*)d_in[12 + 4 * l];
        const float* bt = (const float*)d_in[13 + 4 * l];
        gcn_gemm<<<(NN + 31) / 32, 256, 0, stream>>>(h, Wg, hw);
        gcn_agg<<<NN / 2, 256, 0, stream>>>(hw, off, crow, cw, dinv, bg, gm, bt, h);
    }

    hipMemsetAsync(pooled, 0, HH * sizeof(float), stream);
    pool_k<<<256, 256, 0, stream>>>(h, pooled);
    final_k<<<1, 64, 0, stream>>>(pooled, Wout, bout, out);
}

// Round 7
// 7783.541 us; speedup vs baseline: 1.8668x; 1.1875x over previous
//
#include <hip/hip_runtime.h>

// Problem constants (fixed by the reference)
#define NN 50000
#define TT 200
#define HH 128
#define EE 1600000

// Gate pre-scale constants: i,f,o scaled by -log2(e) so sigmoid = rcp(1+exp2(x));
// g scaled by +2*log2(e) so tanh = 1-2*rcp(exp2(x)+1). Cell state c stays true-scale.
// Numerics verified absmax=0.0 in rounds 1,2,5,6.
// IMPORTANT: use __builtin_amdgcn_exp2f (raw v_exp_f32). exp2f() is the OCML
// precise function with denormal fixup — it made round 6 SLOWER than __expf.
#define NL2E  -1.4426950408889634f
#define TWOL2E 2.8853900817779268f

typedef _Float16 f16x8 __attribute__((ext_vector_type(8)));
typedef float f32x4 __attribute__((ext_vector_type(4)));

__device__ __forceinline__ float sg2(float x) {          // sigmoid(z) for x = -log2e*z
    return __builtin_amdgcn_rcpf(1.f + __builtin_amdgcn_exp2f(x));
}
__device__ __forceinline__ float th2(float x) {          // tanh(z) for x = 2*log2e*z
    return 1.f - 2.f * __builtin_amdgcn_rcpf(__builtin_amdgcn_exp2f(x) + 1.f);
}
__device__ __forceinline__ f32x4 sg2_4(f32x4 x) {
    f32x4 r; r[0] = sg2(x[0]); r[1] = sg2(x[1]); r[2] = sg2(x[2]); r[3] = sg2(x[3]); return r;
}
__device__ __forceinline__ f32x4 th2_4(f32x4 x) {
    f32x4 r; r[0] = th2(x[0]); r[1] = th2(x[1]); r[2] = th2(x[2]); r[3] = th2(x[3]); return r;
}
__device__ __forceinline__ f32x4 splat4(float s) { f32x4 r = {s, s, s, s}; return r; }
__device__ __forceinline__ unsigned short f2h_bits(float x) {
    _Float16 h = (_Float16)x;
    union { _Float16 h; unsigned short u; } cv; cv.h = h; return cv.u;
}
__device__ __forceinline__ float h2f_bits(unsigned short u) {
    union { _Float16 h; unsigned short u; } cv; cv.u = u; return (float)cv.h;
}

// ---------------------------------------------------------------------------
// Weight packing: W is (512,128) row-major (PyTorch [4H, H]).
// MFMA-16x16x32 B-fragment order: tile jn (0..31 over gate-cols), chunk kk (0..3):
// out[(jn*4+kk)*512 + L*8 + i] = W[jn*16 + (L&15)][kk*32 + (L>>4)*8 + i]  (f16)
// Gate pre-scale folded in here (gate = jn>>3; order i,f,g,o).
// ---------------------------------------------------------------------------
__global__ void pack_w(const float* __restrict__ W, unsigned short* __restrict__ out) {
    int tile = blockIdx.x;          // jn*4 + kk
    int jn = tile >> 2, kk = tile & 3;
    int L = threadIdx.x;            // 0..63
    int n = jn * 16 + (L & 15);
    int k0 = kk * 32 + (L >> 4) * 8;
    float sc = ((jn >> 3) == 2) ? TWOL2E : NL2E;
    unsigned short* dst = out + (size_t)tile * 512 + L * 8;
#pragma unroll
    for (int i = 0; i < 8; ++i) dst[i] = f2h_bits(W[n * 128 + k0 + i] * sc);
}

__global__ void bias_prep(const float* __restrict__ bih0, const float* __restrict__ bhh0,
                          const float* __restrict__ bih1, const float* __restrict__ bhh1,
                          const float* __restrict__ wih0,
                          float* __restrict__ b0g, float* __restrict__ b1g, float* __restrict__ wxg) {
    int i = blockIdx.x * 256 + threadIdx.x;
    if (i < 512) {
        float sc = ((i >> 7) == 2) ? TWOL2E : NL2E;
        b0g[i] = (bih0[i] + bhh0[i]) * sc;
        b1g[i] = (bih1[i] + bhh1[i]) * sc;
        wxg[i] = wih0[i] * sc;
    }
}

// lightcurve [N][T] -> xT [T][N]
__global__ void transpose_lc(const float* __restrict__ lc, float* __restrict__ xT) {
    __shared__ float tile[32][33];
    int tx = threadIdx.x, ty = threadIdx.y;    // 32 x 8
    int n0 = blockIdx.y * 32, t0 = blockIdx.x * 32;
#pragma unroll
    for (int i = 0; i < 32; i += 8) {
        int n = n0 + ty + i, t = t0 + tx;
        if (n < NN && t < TT) tile[ty + i][tx] = lc[(size_t)n * TT + t];
    }
    __syncthreads();
#pragma unroll
    for (int i = 0; i < 32; i += 8) {
        int t = t0 + ty + i, n = n0 + tx;
        if (n < NN && t < TT) xT[(size_t)t * NN + n] = tile[tx][ty + i];
    }
}

// ---------------------------------------------------------------------------
// Fused 2-layer LSTM. Block = 512 threads (8 waves), 32 nodes, 200 steps.
// Round-0 structure EXACTLY (two barriers/step, biases staged in LDS — this
// staging is load-bearing for the register allocation; moving biases to
// registers spills: r5). Only change vs round 0: exp2-prescaled gates via
// __builtin_amdgcn_exp2f (one v_mul fewer per transcendental, zero
// register-pressure change).
// ---------------------------------------------------------------------------

#define MFMA16(A, B, C) __builtin_amdgcn_mfma_f32_16x16x32_f16((A), (B), (C), 0, 0, 0)

// One 32-wide K-chunk: 4 B-frags (gates), 2 A-frags (row tiles), 8 MFMAs
#define MMC(HB, PI, PF, PG, PO, KK) {                                          \
    f16x8 bI_ = *reinterpret_cast<const f16x8*>((PI) + (KK) * 512);            \
    f16x8 bF_ = *reinterpret_cast<const f16x8*>((PF) + (KK) * 512);            \
    f16x8 bG_ = *reinterpret_cast<const f16x8*>((PG) + (KK) * 512);            \
    f16x8 bO_ = *reinterpret_cast<const f16x8*>((PO) + (KK) * 512);            \
    f16x8 a0_ = *reinterpret_cast<const f16x8*>(&(HB)[col][(KK) * 32 + quad * 8]);      \
    f16x8 a1_ = *reinterpret_cast<const f16x8*>(&(HB)[16 + col][(KK) * 32 + quad * 8]); \
    aI0 = MFMA16(a0_, bI_, aI0); aI1 = MFMA16(a1_, bI_, aI1);                  \
    aF0 = MFMA16(a0_, bF_, aF0); aF1 = MFMA16(a1_, bF_, aF1);                  \
    aG0 = MFMA16(a0_, bG_, aG0); aG1 = MFMA16(a1_, bG_, aG1);                  \
    aO0 = MFMA16(a0_, bO_, aO0); aO1 = MFMA16(a1_, bO_, aO1);                  \
}

// Activation with x*w_ih terms (layer 0), rowtile RT (rows RT*16+quad*4 ..+3)
#define ACT0N(RT, C, H, AI, AF, AG, AO) {                                      \
    f32x4 xv_ = *reinterpret_cast<const f32x4*>(&xs[(RT) * 16 + quad * 4]);    \
    f32x4 gi_ = AI + splat4(bI) + xv_ * splat4(wI);                            \
    f32x4 gf_ = AF + splat4(bF) + xv_ * splat4(wF);                            \
    f32x4 gg_ = AG + splat4(bG) + xv_ * splat4(wG);                            \
    f32x4 go_ = AO + splat4(bO) + xv_ * splat4(wO);                            \
    C = sg2_4(gf_) * C + sg2_4(gi_) * th2_4(gg_);                              \
    H = sg2_4(go_) * th2_4(C * splat4(TWOL2E));                                \
}

// Activation, no x terms (layer 1)
#define ACT1N(C, H, AI, AF, AG, AO) {                                          \
    f32x4 gi_ = AI + splat4(bI);                                               \
    f32x4 gf_ = AF + splat4(bF);                                               \
    f32x4 gg_ = AG + splat4(bG);                                               \
    f32x4 go_ = AO + splat4(bO);                                               \
    C = sg2_4(gf_) * C + sg2_4(gi_) * th2_4(gg_);                              \
    H = sg2_4(go_) * th2_4(C * splat4(TWOL2E));                                \
}

// Write rowtile RT of this wave's h (f16) into LDS buffer
#define WRH(HB, RT, H)                                                         \
    (HB)[(RT) * 16 + quad * 4 + 0][j_] = f2h_bits((H)[0]);                     \
    (HB)[(RT) * 16 + quad * 4 + 1][j_] = f2h_bits((H)[1]);                     \
    (HB)[(RT) * 16 + quad * 4 + 2][j_] = f2h_bits((H)[2]);                     \
    (HB)[(RT) * 16 + quad * 4 + 3][j_] = f2h_bits((H)[3]);

// One timestep: PB = write buffer (t&1), RB = read buffer (PB^1)
#define STEP(PB, RB, T)                                                        \
    {   /* layer 0: gates = h1_old @ Whh0^T + x*wih0 + b0 */                   \
        f32x4 aI0 = {}, aI1 = {}, aF0 = {}, aF1 = {};                          \
        f32x4 aG0 = {}, aG1 = {}, aO0 = {}, aO1 = {};                          \
        MMC(h1s[RB], p0I, p0F, p0G, p0O, 0)                                    \
        MMC(h1s[RB], p0I, p0F, p0G, p0O, 1)                                    \
        MMC(h1s[RB], p0I, p0F, p0G, p0O, 2)                                    \
        MMC(h1s[RB], p0I, p0F, p0G, p0O, 3)                                    \
        const float bI = b0s[j_], bF = b0s[128 + j_];                          \
        const float bG = b0s[256 + j_], bO = b0s[384 + j_];                    \
        const float wI = wxs[j_], wF = wxs[128 + j_];                          \
        const float wG = wxs[256 + j_], wO = wxs[384 + j_];                    \
        f32x4 h1v0, h1v1;                                                      \
        ACT0N(0, c1_0, h1v0, aI0, aF0, aG0, aO0)                               \
        ACT0N(1, c1_1, h1v1, aI1, aF1, aG1, aO1)                               \
        WRH(h1s[PB], 0, h1v0)                                                  \
        WRH(h1s[PB], 1, h1v1)                                                  \
    }                                                                          \
    __syncthreads();                                                           \
    {   /* layer 1: gates = h1_new @ Wih1^T + h2_old @ Whh1^T + b1 */          \
        f32x4 aI0 = {}, aI1 = {}, aF0 = {}, aF1 = {};                          \
        f32x4 aG0 = {}, aG1 = {}, aO0 = {}, aO1 = {};                          \
        MMC(h1s[PB], u0I, u0F, u0G, u0O, 0)                                    \
        MMC(h1s[PB], u0I, u0F, u0G, u0O, 1)                                    \
        MMC(h1s[PB], u0I, u0F, u0G, u0O, 2)                                    \
        MMC(h1s[PB], u0I, u0F, u0G, u0O, 3)                                    \
        MMC(h2s[RB], v0I, v0F, v0G, v0O, 0)                                    \
        MMC(h2s[RB], v0I, v0F, v0G, v0O, 1)                                    \
        MMC(h2s[RB], v0I, v0F, v0G, v0O, 2)                                    \
        MMC(h2s[RB], v0I, v0F, v0G, v0O, 3)                                    \
        if (tid < 32) {   /* prefetch x[T+1] while ACT runs */                 \
            int n_ = n0 + tid;                                                 \
            xs[tid] = ((T) + 1 < TT && n_ < NN)                                \
                          ? xT[(size_t)((T) + 1) * NN + n_] : 0.f;             \
        }                                                                      \
        const float bI = b1s[j_], bF = b1s[128 + j_];                          \
        const float bG = b1s[256 + j_], bO = b1s[384 + j_];                    \
        f32x4 h2v0, h2v1;                                                      \
        ACT1N(c2_0, h2v0, aI0, aF0, aG0, aO0)                                  \
        ACT1N(c2_1, h2v1, aI1, aF1, aG1, aO1)                                  \
        WRH(h2s[PB], 0, h2v0)                                                  \
        WRH(h2s[PB], 1, h2v1)                                                  \
    }                                                                          \
    __syncthreads();

__global__ __launch_bounds__(512, 2) void lstm_kernel(
    const float* __restrict__ xT,
    const unsigned short* __restrict__ w0p,
    const unsigned short* __restrict__ w1ip,
    const unsigned short* __restrict__ w1hp,
    const float* __restrict__ b0g, const float* __restrict__ b1g,
    const float* __restrict__ wxg,
    float* __restrict__ h2out) {
    __shared__ unsigned short h1s[2][32][136];   // double-buffered, f16
    __shared__ unsigned short h2s[2][32][136];
    __shared__ __align__(16) float xs[32];
    __shared__ float b0s[512], b1s[512], wxs[512];

    const int tid = threadIdx.x;
    const int w = tid >> 6;          // wave id 0..7 == col-group jt
    const int lane = tid & 63;
    const int col = lane & 15;
    const int quad = lane >> 4;
    const int n0 = blockIdx.x * 32;
    const int j_ = w * 16 + col;     // this lane's hidden column

    for (int i = tid; i < 2 * 32 * 136; i += 512) {
        (&h1s[0][0][0])[i] = 0; (&h2s[0][0][0])[i] = 0;
    }
    if (tid < 512) { b0s[tid] = b0g[tid]; b1s[tid] = b1g[tid]; wxs[tid] = wxg[tid]; }
    if (tid < 32) { int n = n0 + tid; xs[tid] = (n < NN) ? xT[n] : 0.f; }

    // B-fragment base pointers (gate g tile = 8g + jt; tile stride 2048 ushorts)
    const unsigned short* p0I = w0p + (size_t)w * 2048 + lane * 8;
    const unsigned short* p0F = w0p + (size_t)(8 + w) * 2048 + lane * 8;
    const unsigned short* p0G = w0p + (size_t)(16 + w) * 2048 + lane * 8;
    const unsigned short* p0O = w0p + (size_t)(24 + w) * 2048 + lane * 8;
    const unsigned short* u0I = w1ip + (size_t)w * 2048 + lane * 8;
    const unsigned short* u0F = w1ip + (size_t)(8 + w) * 2048 + lane * 8;
    const unsigned short* u0G = w1ip + (size_t)(16 + w) * 2048 + lane * 8;
    const unsigned short* u0O = w1ip + (size_t)(24 + w) * 2048 + lane * 8;
    const unsigned short* v0I = w1hp + (size_t)w * 2048 + lane * 8;
    const unsigned short* v0F = w1hp + (size_t)(8 + w) * 2048 + lane * 8;
    const unsigned short* v0G = w1hp + (size_t)(16 + w) * 2048 + lane * 8;
    const unsigned short* v0O = w1hp + (size_t)(24 + w) * 2048 + lane * 8;

    // persistent cell state: 4 f32x4 = 16 regs
    f32x4 c1_0 = {}, c1_1 = {}, c2_0 = {}, c2_1 = {};

    __syncthreads();

#pragma unroll 1
    for (int tt = 0; tt < TT; tt += 2) {
        STEP(0, 1, tt)
        STEP(1, 0, tt + 1)
    }

    // final h2 lives in buffer 1 (last step wrote PB=1); cooperative write-out
    for (int i = tid; i < 32 * 128; i += 512) {
        int m = i >> 7, j = i & 127;
        int n = n0 + m;
        if (n < NN) h2out[(size_t)n * HH + j] = h2f_bits(h2s[1][m][j]);
    }
}

// ---------------------------------------------------------------------------
// GCN pieces (fp32)
// ---------------------------------------------------------------------------
__global__ void deg_init(float* __restrict__ deg) {
    int i = blockIdx.x * 256 + threadIdx.x;
    if (i < NN) deg[i] = 1.f;   // self loop
}
__global__ void deg_edges(const int* __restrict__ ei, float* __restrict__ deg) {
    int e = blockIdx.x * 256 + threadIdx.x;
    if (e < EE) unsafeAtomicAdd(&deg[ei[EE + e]], 1.f);   // col = target
}
__global__ void dinv_k(const float* __restrict__ deg, float* __restrict__ dinv) {
    int i = blockIdx.x * 256 + threadIdx.x;
    if (i < NN) dinv[i] = rsqrtf(fmaxf(deg[i], 1.f));
}

// exclusive scan of per-node in-edge counts (deg-1) -> off[0..NN]
__global__ void scan_off(const float* __restrict__ deg, int* __restrict__ off) {
    __shared__ int sp[256];
    const int tid = threadIdx.x;
    const int chunk = (NN + 255) / 256;
    const int i0 = tid * chunk;
    int s = 0;
    for (int i = 0; i < chunk; ++i) {
        int idx = i0 + i;
        if (idx < NN) s += (int)deg[idx] - 1;
    }
    sp[tid] = s;
    __syncthreads();
    for (int o = 1; o < 256; o <<= 1) {
        int v = (tid >= o) ? sp[tid - o] : 0;
        __syncthreads();
        sp[tid] += v;
        __syncthreads();
    }
    int run = sp[tid] - s;
    for (int i = 0; i < chunk; ++i) {
        int idx = i0 + i;
        if (idx < NN) { off[idx] = run; run += (int)deg[idx] - 1; }
    }
    if (tid == 255) off[NN] = sp[255];
}

__global__ void csr_fill(const int* __restrict__ ei, const float* __restrict__ dinv,
                         const int* __restrict__ off, int* __restrict__ cur,
                         int* __restrict__ crow, float* __restrict__ cw) {
    int e = blockIdx.x * 256 + threadIdx.x;
    if (e >= EE) return;
    int r = ei[e], c = ei[EE + e];
    int p = atomicAdd(&cur[c], 1);
    int idx = off[c] + p;
    crow[idx] = r;
    cw[idx] = dinv[r] * dinv[c];
}

// hw = h @ Wg   ([N,128] x [128,128]); 32 nodes per block
__global__ void gcn_gemm(const float* __restrict__ h, const float* __restrict__ Wg,
                         float* __restrict__ hw) {
    __shared__ float hsT[128][36];
    int tid = threadIdx.x;
    int n0 = blockIdx.x * 32;
#pragma unroll
    for (int c = 0; c < 16; ++c) {
        int lin = c * 256 + tid;
        int m = lin >> 7, k = lin & 127;
        int n = n0 + m;
        hsT[k][m] = (n < NN) ? h[(size_t)n * HH + k] : 0.f;
    }
    __syncthreads();
    int j = tid & 127, p = tid >> 7;
    float acc[16];
#pragma unroll
    for (int m = 0; m < 16; ++m) acc[m] = 0.f;
    for (int k = 0; k < 128; ++k) {
        float wg = Wg[k * 128 + j];
        const float4* hp = reinterpret_cast<const float4*>(&hsT[k][p * 16]);
        float4 a = hp[0], b = hp[1], c = hp[2], d = hp[3];
        acc[0]  += a.x * wg; acc[1]  += a.y * wg; acc[2]  += a.z * wg; acc[3]  += a.w * wg;
        acc[4]  += b.x * wg; acc[5]  += b.y * wg; acc[6]  += b.z * wg; acc[7]  += b.w * wg;
        acc[8]  += c.x * wg; acc[9]  += c.y * wg; acc[10] += c.z * wg; acc[11] += c.w * wg;
        acc[12] += d.x * wg; acc[13] += d.y * wg; acc[14] += d.z * wg; acc[15] += d.w * wg;
    }
#pragma unroll
    for (int m = 0; m < 16; ++m) {
        int n = n0 + p * 16 + m;
        if (n < NN) hw[(size_t)n * HH + j] = acc[m];
    }
}

// Fused: self-loop + CSR gather + bias + LayerNorm + ReLU + residual
__global__ __launch_bounds__(256) void gcn_agg(
    const float* __restrict__ hw, const int* __restrict__ off,
    const int* __restrict__ crow, const float* __restrict__ cw,
    const float* __restrict__ dinv, const float* __restrict__ bg,
    const float* __restrict__ gamma, const float* __restrict__ beta,
    float* __restrict__ h) {
    __shared__ float xch[4][2];
    const int tid = threadIdx.x;
    const int half = tid >> 7;
    const int f = tid & 127;
    const int v = blockIdx.x * 2 + half;
    const float d = dinv[v];
    float acc = bg[f] + d * d * hw[v * HH + f];
    const int s1 = off[v + 1];
    for (int s = off[v]; s < s1; ++s) {
        int r = crow[s];
        float wv = cw[s];
        acc = fmaf(wv, hw[r * HH + f], acc);
    }
    float sum = acc, sq = acc * acc;
#pragma unroll
    for (int o = 32; o; o >>= 1) { sum += __shfl_xor(sum, o); sq += __shfl_xor(sq, o); }
    int wid = tid >> 6;
    if ((tid & 63) == 0) { xch[wid][0] = sum; xch[wid][1] = sq; }
    __syncthreads();
    sum += xch[wid ^ 1][0]; sq += xch[wid ^ 1][1];
    float mu = sum * (1.f / 128.f);
    float var = sq * (1.f / 128.f) - mu * mu;
    float rn = rsqrtf(var + 1e-5f);
    float o = (acc - mu) * rn * gamma[f] + beta[f];
    h[v * HH + f] = fmaxf(o, 0.f) + h[v * HH + f];
}

__global__ void pool_k(const float* __restrict__ h, float* __restrict__ pooled) {
    int j = threadIdx.x & 127, p = threadIdx.x >> 7;
    float s = 0.f;
    for (int n = blockIdx.x * 2 + p; n < NN; n += 512) s += h[(size_t)n * HH + j];
    unsafeAtomicAdd(&pooled[j], s);
}

__global__ void final_k(const float* __restrict__ pooled, const float* __restrict__ Wout,
                        const float* __restrict__ bout, float* __restrict__ out) {
    int lane = threadIdx.x;
    float s = pooled[lane] * Wout[lane] + pooled[lane + 64] * Wout[lane + 64];
#pragma unroll
    for (int o = 32; o; o >>= 1) s += __shfl_xor(s, o);
    if (lane == 0) out[0] = s * (1.f / (float)NN) + bout[0];
}

// ---------------------------------------------------------------------------
extern "C" void kernel_launch(void* const* d_in, const int* in_sizes, int n_in,
                              void* d_out, int out_size, void* d_ws, size_t ws_size,
                              hipStream_t stream) {
    const float* lc   = (const float*)d_in[0];
    const int*   ei   = (const int*)d_in[1];
    const float* Wih0 = (const float*)d_in[2];
    const float* Whh0 = (const float*)d_in[3];
    const float* bih0 = (const float*)d_in[4];
    const float* bhh0 = (const float*)d_in[5];
    const float* Wih1 = (const float*)d_in[6];
    const float* Whh1 = (const float*)d_in[7];
    const float* bih1 = (const float*)d_in[8];
    const float* bhh1 = (const float*)d_in[9];
    const float* Wout = (const float*)d_in[22];
    const float* bout = (const float*)d_in[23];
    float* out = (float*)d_out;

    float* ws   = (float*)d_ws;
    float* h    = ws;
    float* hw   = ws + 6400000;
    float* xT   = ws + 6400000;                    // aliases hw+CSR region pre-LSTM
    int*   off  = (int*)(ws + 12800000);
    int*   cur  = off + 50048;
    int*   crow = cur + 50048;
    float* cw   = (float*)(crow + EE);
    float* P      = ws + 16400064;
    float* deg    = P;
    float* dinv   = deg + 50000;
    float* b0g    = dinv + 50000;
    float* b1g    = b0g + 512;
    float* wxg    = b1g + 512;
    float* pooled = wxg + 512;
    unsigned short* w0p  = (unsigned short*)(pooled + 128);
    unsigned short* w1ip = w0p + 65536;
    unsigned short* w1hp = w1ip + 65536;

    pack_w<<<128, 64, 0, stream>>>(Whh0, w0p);
    pack_w<<<128, 64, 0, stream>>>(Wih1, w1ip);
    pack_w<<<128, 64, 0, stream>>>(Whh1, w1hp);
    bias_prep<<<2, 256, 0, stream>>>(bih0, bhh0, bih1, bhh1, Wih0, b0g, b1g, wxg);
    {
        dim3 g((TT + 31) / 32, (NN + 31) / 32), b(32, 8);
        transpose_lc<<<g, b, 0, stream>>>(lc, xT);
    }
    deg_init<<<(NN + 255) / 256, 256, 0, stream>>>(deg);
    deg_edges<<<(EE + 255) / 256, 256, 0, stream>>>(ei, deg);
    dinv_k<<<(NN + 255) / 256, 256, 0, stream>>>(deg, dinv);

    lstm_kernel<<<(NN + 31) / 32, 512, 0, stream>>>(xT, w0p, w1ip, w1hp, b0g, b1g, wxg, h);

    hipMemsetAsync(cur, 0, 50000 * sizeof(int), stream);
    scan_off<<<1, 256, 0, stream>>>(deg, off);
    csr_fill<<<(EE + 255) / 256, 256, 0, stream>>>(ei, dinv, off, cur, crow, cw);

    for (int l = 0; l < 3; ++l) {
        const float* Wg = (const float*)d_in[10 + 4 * l];
        const float* bg = (const float*)d_in[11 + 4 * l];
        const float* gm = (const float*)d_in[12 + 4 * l];
        const float* bt = (const float*)d_in[13 + 4 * l];
        gcn_gemm<<<(NN + 31) / 32, 256, 0, stream>>>(h, Wg, hw);
        gcn_agg<<<NN / 2, 256, 0, stream>>>(hw, off, crow, cw, dinv, bg, gm, bt, h);
    }

    hipMemsetAsync(pooled, 0, HH * sizeof(float), stream);
    pool_k<<<256, 256, 0, stream>>>(h, pooled);
    final_k<<<1, 64, 0, stream>>>(pooled, Wout, bout, out);
}